// Round 5
// baseline (4792.153 us; speedup 1.0000x reference)
//
#include <hip/hip_runtime.h>
#include <hip/hip_bf16.h>

// Problem constants: inputs [T,B,D], state [B,H], W_xh [D,H], W_hh [H,H], b_h [H]
#define T_STEPS 256
#define B_SZ    64
#define D_SZ    1024
#define H_SZ    2048
#define NBLK    64      // persistent blocks (coop-launched, 1 per CU max)

// fp16 everywhere (2^-11 rounding). Weights stored x256 so all entries are
// fp16-normal (W ~ U(0,0.01)); accumulator scaled by 1/256 in epilogue.
#define W_SCALE     256.0f
#define W_INV_SCALE 0.00390625f

typedef __attribute__((ext_vector_type(8))) _Float16 f16x8;  // 8 fp16 (4 VGPRs)
typedef __attribute__((ext_vector_type(4))) float    f32x4;  // MFMA 16x16 accumulator

// ---------------- conversion kernels ----------------

__global__ void cvt_f32_f16(const float* __restrict__ in,
                            _Float16* __restrict__ out, int n, float scale) {
    int i = blockIdx.x * blockDim.x + threadIdx.x;
    if (i < n) out[i] = (_Float16)(in[i] * scale);
}

// in[rows][cols] (fp32) -> out[cols][rows] (fp16, scaled). cols = 1<<log2cols.
__global__ void transpose_to_f16(const float* __restrict__ in,
                                 _Float16* __restrict__ out,
                                 int rows, int log2cols, float scale) {
    int i = blockIdx.x * blockDim.x + threadIdx.x;
    int cols = 1 << log2cols;
    if (i >= rows * cols) return;
    int r = i >> log2cols;
    int c = i & (cols - 1);
    out[c * rows + r] = (_Float16)(in[i] * scale);
}

__global__ void init_ctr(unsigned int* ctr) { *ctr = 0u; }

// ---------------- phase 1: x_proj = inputs @ W_xh + b_h ----------------
// A [M,K] fp16 row-major, BT [N,K] fp16 (W_xh^T, x256), C [M,N] fp32.
__global__ __launch_bounds__(256) void gemm_xproj(
    const _Float16* __restrict__ A,
    const _Float16* __restrict__ BT,
    const float* __restrict__ bias,
    float* __restrict__ C,
    int M, int N, int K)
{
    int wave = threadIdx.x >> 6;
    int lane = threadIdx.x & 63;
    int q = lane >> 4;          // quad: k = q*8 + j for A/B fragments
    int r = lane & 15;          // row (A) / col (B) within 16
    int m0 = blockIdx.x * 128 + (wave >> 1) * 64;
    int n0 = blockIdx.y * 128 + (wave & 1) * 64;

    f32x4 acc[4][4] = {};
    for (int k = 0; k < K; k += 32) {
        int kk = k + q * 8;
        f16x8 a[4], b[4];
#pragma unroll
        for (int i = 0; i < 4; i++)
            a[i] = *(const f16x8*)(A + (size_t)(m0 + i * 16 + r) * K + kk);
#pragma unroll
        for (int j = 0; j < 4; j++)
            b[j] = *(const f16x8*)(BT + (size_t)(n0 + j * 16 + r) * K + kk);
#pragma unroll
        for (int i = 0; i < 4; i++)
#pragma unroll
            for (int j = 0; j < 4; j++)
                acc[i][j] = __builtin_amdgcn_mfma_f32_16x16x32_f16(a[i], b[j], acc[i][j], 0, 0, 0);
    }
#pragma unroll
    for (int i = 0; i < 4; i++)
#pragma unroll
        for (int j = 0; j < 4; j++)
#pragma unroll
            for (int reg = 0; reg < 4; reg++) {
                int row = m0 + i * 16 + q * 4 + reg;   // C/D: col=lane&15, row=(lane>>4)*4+reg
                int col = n0 + j * 16 + r;
                C[(size_t)row * N + col] = acc[i][j][reg] * W_INV_SCALE + bias[col];
            }
}

// ---------------- phase 2: persistent recurrence, fence-free ----------------
// 64 blocks x 256 thr (4 waves). Block owns 32 output columns; W_hh^T slice
// [32 cols][2048 k] pre-swizzled into LDS in MFMA B-fragment order (128 KB).
// Wave w computes rows [16w,16w+16) x 32 cols, full K=2048 (no cross-wave reduce).
// Cross-block h traffic is ONLY via relaxed agent-scope atomics (sc1: bypass
// L1/L2, served by device-coherent MALL) -> zero per-step cache maintenance.
// R3 lesson: release/acquire fences cost ~13 us/step in buffer_wbl2/buffer_inv.
// Ordering: __syncthreads drains vmcnt (store acks from coherence point) before
// the barrier add; MALL serializes h-stores < ctr-add < ctr-poll < h-loads.
__global__ __launch_bounds__(256, 1) void rnn_persist(
    _Float16* __restrict__ hb0,            // [B,H] fp16 ping (holds h_0)
    _Float16* __restrict__ hb1,            // [B,H] fp16 pong
    const _Float16* __restrict__ WT,       // [H,H] fp16 = W_hh^T x256
    float* __restrict__ out,               // [T,B,H] fp32: x_proj in, h out (in place)
    float* __restrict__ final_out,         // [B,H] fp32
    unsigned int* __restrict__ ctr)        // barrier counter (pre-zeroed)
{
    __shared__ f16x8 wfrag[8192];                     // 64 kb x 2 j x 64 lanes = 128 KB
    __shared__ __align__(16) _Float16 hsl[64 * 32];   // 4 KB h-slice repack

    int tid = threadIdx.x;
    int n0 = blockIdx.x * 32;

    // one-time W staging into fragment order: idx = (kb*2+j)*64 + l
    for (int idx = tid; idx < 8192; idx += 256) {
        int kb = idx >> 7, j = (idx >> 6) & 1, l = idx & 63;
        wfrag[idx] = *(const f16x8*)(WT + (size_t)(n0 + j * 16 + (l & 15)) * H_SZ
                                        + kb * 32 + (l >> 4) * 8);
    }
    __syncthreads();

    int wave = tid >> 6, lane = tid & 63;
    int q = lane >> 4, r = lane & 15;
    int row0 = wave * 16;                  // this wave's 16 batch rows

    for (int t = 0; t < T_STEPS; t++) {
        const _Float16* hp = (t & 1) ? hb1 : hb0;
        _Float16*       hn = (t & 1) ? hb0 : hb1;
        float* out_t = out + (size_t)t * B_SZ * H_SZ;

        // x_proj prefetch (block-private region of out; plain loads)
        float xp[2][4];
#pragma unroll
        for (int j = 0; j < 2; j++)
#pragma unroll
            for (int reg = 0; reg < 4; reg++)
                xp[j][reg] = out_t[(size_t)(row0 + q * 4 + reg) * H_SZ + n0 + j * 16 + r];

        f32x4 acc[2] = {};
        const unsigned long long* arow =
            (const unsigned long long*)(hp + (size_t)(row0 + r) * H_SZ + q * 8);
        // arow stride per kb: 32 fp16 = 64 B = 8 ull
#pragma unroll 8
        for (int kb = 0; kb < 64; kb++) {
            union { unsigned long long u[2]; f16x8 v; } a;
            a.u[0] = __hip_atomic_load((unsigned long long*)(arow + kb * 8),
                                       __ATOMIC_RELAXED, __HIP_MEMORY_SCOPE_AGENT);
            a.u[1] = __hip_atomic_load((unsigned long long*)(arow + kb * 8 + 1),
                                       __ATOMIC_RELAXED, __HIP_MEMORY_SCOPE_AGENT);
            acc[0] = __builtin_amdgcn_mfma_f32_16x16x32_f16(a.v, wfrag[kb * 128 + lane],      acc[0], 0, 0, 0);
            acc[1] = __builtin_amdgcn_mfma_f32_16x16x32_f16(a.v, wfrag[kb * 128 + 64 + lane], acc[1], 0, 0, 0);
        }

        // epilogue: tanh, fp32 out, fp16 h into LDS for coalesced coherent store
#pragma unroll
        for (int j = 0; j < 2; j++)
#pragma unroll
            for (int reg = 0; reg < 4; reg++) {
                int row = row0 + q * 4 + reg;
                int cl  = j * 16 + r;
                float v = tanhf(acc[j][reg] * W_INV_SCALE + xp[j][reg]);
                out_t[(size_t)row * H_SZ + n0 + cl] = v;
                hsl[row * 32 + cl] = (_Float16)v;
                if (t == T_STEPS - 1) final_out[(size_t)row * H_SZ + n0 + cl] = v;
            }
        __syncthreads();   // hsl complete

        // coherent h store: 64 rows x 32 cols = 512 x 8B, coalesced, to MALL
        for (int idx = tid; idx < 512; idx += 256) {
            int row = idx >> 3, part = idx & 7;
            unsigned long long vv = ((const unsigned long long*)(hsl + row * 32))[part];
            __hip_atomic_store((unsigned long long*)(hn + (size_t)row * H_SZ + n0) + part,
                               vv, __ATOMIC_RELAXED, __HIP_MEMORY_SCOPE_AGENT);
        }
        if (t == T_STEPS - 1) break;

        __syncthreads();   // all waves' h stores drained (vmcnt 0) before arrival
        if (tid == 0) {
            __hip_atomic_fetch_add(ctr, 1u, __ATOMIC_RELAXED, __HIP_MEMORY_SCOPE_AGENT);
            unsigned int target = (unsigned int)(t + 1) * NBLK;
            while (__hip_atomic_load(ctr, __ATOMIC_RELAXED, __HIP_MEMORY_SCOPE_AGENT) < target)
                __builtin_amdgcn_s_sleep(1);
        }
        __syncthreads();   // no acquire fence: h loads bypass caches anyway
    }
}

// ---------------- launcher ----------------

extern "C" void kernel_launch(void* const* d_in, const int* in_sizes, int n_in,
                              void* d_out, int out_size, void* d_ws, size_t ws_size,
                              hipStream_t stream) {
    const float* inputs = (const float*)d_in[0];   // [T,B,D]
    const float* state  = (const float*)d_in[1];   // [B,H]
    const float* W_xh   = (const float*)d_in[2];   // [D,H]
    const float* W_hh   = (const float*)d_in[3];   // [H,H]
    const float* b_h    = (const float*)d_in[4];   // [H]
    float* out = (float*)d_out;

    // workspace layout (fp16 buffers + barrier counter)
    const size_t OFF_IN   = 0;                                     // T*B*D fp16
    const size_t OFF_WXT  = OFF_IN  + (size_t)T_STEPS*B_SZ*D_SZ*2; // [H,D] fp16
    const size_t OFF_WHT  = OFF_WXT + (size_t)H_SZ*D_SZ*2;         // [H,H] fp16
    const size_t OFF_H0   = OFF_WHT + (size_t)H_SZ*H_SZ*2;         // [B,H] fp16
    const size_t OFF_H1   = OFF_H0  + (size_t)B_SZ*H_SZ*2;
    const size_t OFF_CTR  = OFF_H1  + (size_t)B_SZ*H_SZ*2;
    const size_t NEED     = OFF_CTR + 64;
    if (ws_size < NEED) return;  // insufficient scratch

    char* ws = (char*)d_ws;
    _Float16* inputs_f16 = (_Float16*)(ws + OFF_IN);
    _Float16* WxT        = (_Float16*)(ws + OFF_WXT);
    _Float16* WhT        = (_Float16*)(ws + OFF_WHT);
    _Float16* hbuf0      = (_Float16*)(ws + OFF_H0);
    _Float16* hbuf1      = (_Float16*)(ws + OFF_H1);
    unsigned int* ctr    = (unsigned int*)(ws + OFF_CTR);

    const int n_in_el = T_STEPS * B_SZ * D_SZ;   // 16,777,216
    cvt_f32_f16<<<(n_in_el + 255) / 256, 256, 0, stream>>>(inputs, inputs_f16, n_in_el, 1.0f);
    transpose_to_f16<<<(D_SZ * H_SZ + 255) / 256, 256, 0, stream>>>(W_xh, WxT, D_SZ, 11, W_SCALE);
    transpose_to_f16<<<(H_SZ * H_SZ + 255) / 256, 256, 0, stream>>>(W_hh, WhT, H_SZ, 11, W_SCALE);
    cvt_f32_f16<<<(B_SZ * H_SZ + 255) / 256, 256, 0, stream>>>(state, hbuf0, B_SZ * H_SZ, 1.0f);
    init_ctr<<<1, 1, 0, stream>>>(ctr);   // ws is re-poisoned before every launch

    // phase 1: x_proj -> d_out[0 : T*B*H]
    dim3 g1((T_STEPS * B_SZ) / 128, H_SZ / 128);
    gemm_xproj<<<g1, 256, 0, stream>>>(inputs_f16, WxT, b_h, out,
                                       T_STEPS * B_SZ, H_SZ, D_SZ);

    // phase 2: one cooperative dispatch (co-residency guarantee), own barrier
    float* final_out = out + (size_t)T_STEPS * B_SZ * H_SZ;
    void* args[] = { (void*)&hbuf0, (void*)&hbuf1, (void*)&WhT,
                     (void*)&out, (void*)&final_out, (void*)&ctr };
    hipLaunchCooperativeKernel((void*)rnn_persist, dim3(NBLK), dim3(256),
                               args, 0, stream);
}

// Round 6
// 4015.344 us; speedup vs baseline: 1.1935x; 1.1935x over previous
//
#include <hip/hip_runtime.h>
#include <hip/hip_bf16.h>

// Problem constants: inputs [T,B,D], state [B,H], W_xh [D,H], W_hh [H,H], b_h [H]
#define T_STEPS 256
#define B_SZ    64
#define D_SZ    1024
#define H_SZ    2048
#define NBLK    64      // persistent blocks (coop-launched)
#define HBUF    (B_SZ * H_SZ)   // one h buffer: 131072 fp16 = 256 KB

// fp16 everywhere (2^-11 rounding). Weights stored x256 so all entries are
// fp16-normal (W ~ U(0,0.01)); accumulator scaled by 1/256 in epilogue.
#define W_SCALE     256.0f
#define W_INV_SCALE 0.00390625f

typedef __attribute__((ext_vector_type(8))) _Float16 f16x8;  // 8 fp16 (4 VGPRs)
typedef __attribute__((ext_vector_type(4))) float    f32x4;  // MFMA 16x16 accumulator

// ---------------- conversion kernels ----------------

__global__ void cvt_f32_f16(const float* __restrict__ in,
                            _Float16* __restrict__ out, int n, float scale) {
    int i = blockIdx.x * blockDim.x + threadIdx.x;
    if (i < n) out[i] = (_Float16)(in[i] * scale);
}

// in[rows][cols] (fp32) -> out[cols][rows] (fp16, scaled). cols = 1<<log2cols.
__global__ void transpose_to_f16(const float* __restrict__ in,
                                 _Float16* __restrict__ out,
                                 int rows, int log2cols, float scale) {
    int i = blockIdx.x * blockDim.x + threadIdx.x;
    int cols = 1 << log2cols;
    if (i >= rows * cols) return;
    int r = i >> log2cols;
    int c = i & (cols - 1);
    out[c * rows + r] = (_Float16)(in[i] * scale);
}

__global__ void init_ctr(unsigned int* ctr) { *ctr = 0u; }

// ---------------- phase 1: x_proj = inputs @ W_xh + b_h ----------------
// A [M,K] fp16 row-major, BT [N,K] fp16 (W_xh^T, x256), C [M,N] fp32.
__global__ __launch_bounds__(256) void gemm_xproj(
    const _Float16* __restrict__ A,
    const _Float16* __restrict__ BT,
    const float* __restrict__ bias,
    float* __restrict__ C,
    int M, int N, int K)
{
    int wave = threadIdx.x >> 6;
    int lane = threadIdx.x & 63;
    int q = lane >> 4;          // quad: k = q*8 + j for A/B fragments
    int r = lane & 15;          // row (A) / col (B) within 16
    int m0 = blockIdx.x * 128 + (wave >> 1) * 64;
    int n0 = blockIdx.y * 128 + (wave & 1) * 64;

    f32x4 acc[4][4] = {};
    for (int k = 0; k < K; k += 32) {
        int kk = k + q * 8;
        f16x8 a[4], b[4];
#pragma unroll
        for (int i = 0; i < 4; i++)
            a[i] = *(const f16x8*)(A + (size_t)(m0 + i * 16 + r) * K + kk);
#pragma unroll
        for (int j = 0; j < 4; j++)
            b[j] = *(const f16x8*)(BT + (size_t)(n0 + j * 16 + r) * K + kk);
#pragma unroll
        for (int i = 0; i < 4; i++)
#pragma unroll
            for (int j = 0; j < 4; j++)
                acc[i][j] = __builtin_amdgcn_mfma_f32_16x16x32_f16(a[i], b[j], acc[i][j], 0, 0, 0);
    }
#pragma unroll
    for (int i = 0; i < 4; i++)
#pragma unroll
        for (int j = 0; j < 4; j++)
#pragma unroll
            for (int reg = 0; reg < 4; reg++) {
                int row = m0 + i * 16 + q * 4 + reg;   // C/D: col=lane&15, row=(lane>>4)*4+reg
                int col = n0 + j * 16 + r;
                C[(size_t)row * N + col] = acc[i][j][reg] * W_INV_SCALE + bias[col];
            }
}

// ---------------- phase 2: persistent recurrence ----------------
// R1/R3/R4 all hit ~16.8 us/step: 64 blocks x 256 KB fresh-h reads/step through
// MALL = 16 MB/step at ~1 TB/s (64-way line sharing hotspot). Fix (CHAIN=true):
// each step writes a FRESH buffer h_t (no address reuse) via sc1 write-through
// atomic stores; readers use PLAIN cached loads -> first touch after the
// barrier misses L2, fetches fresh from MALL, 7 sibling blocks on the XCD hit
// L2. MALL traffic 16 -> 2 MB/step. No fences, no invalidates ever.
// CHAIN=false is the R4 ping-pong fallback (bypass atomic loads) if ws is small.
template<bool CHAIN>
__global__ __launch_bounds__(256, 1) void rnn_persist(
    _Float16* __restrict__ hbase,          // CHAIN: h_0 of chain; else ping buf
    _Float16* __restrict__ hb1,            // pong buf (fallback only)
    const _Float16* __restrict__ WT,       // [H,H] fp16 = W_hh^T x256
    float* __restrict__ out,               // [T,B,H] fp32: x_proj in, h out (in place)
    float* __restrict__ final_out,         // [B,H] fp32
    unsigned int* __restrict__ ctr)        // barrier counter (pre-zeroed)
{
    __shared__ f16x8 wfrag[8192];                     // 64 kb x 2 j x 64 lanes = 128 KB
    __shared__ __align__(16) _Float16 hsl[64 * 32];   // 4 KB h-slice repack

    int tid = threadIdx.x;
    int n0 = blockIdx.x * 32;

    // one-time W staging into fragment order: idx = (kb*2+j)*64 + l
    for (int idx = tid; idx < 8192; idx += 256) {
        int kb = idx >> 7, j = (idx >> 6) & 1, l = idx & 63;
        wfrag[idx] = *(const f16x8*)(WT + (size_t)(n0 + j * 16 + (l & 15)) * H_SZ
                                        + kb * 32 + (l >> 4) * 8);
    }
    __syncthreads();

    int wave = tid >> 6, lane = tid & 63;
    int q = lane >> 4, r = lane & 15;
    int row0 = wave * 16;                  // this wave's 16 batch rows

    // x_proj prefetch for t=0 (block-private region of out; plain loads)
    float xp[2][4];
#pragma unroll
    for (int j = 0; j < 2; j++)
#pragma unroll
        for (int reg = 0; reg < 4; reg++)
            xp[j][reg] = out[(size_t)(row0 + q * 4 + reg) * H_SZ + n0 + j * 16 + r];

    for (int t = 0; t < T_STEPS; t++) {
        const _Float16* hp;
        _Float16*       hn;
        if constexpr (CHAIN) {
            hp = hbase + (size_t)t * HBUF;
            hn = hbase + (size_t)(t + 1) * HBUF;
        } else {
            hp = (t & 1) ? hb1 : hbase;
            hn = (t & 1) ? hbase : hb1;
        }
        float* out_t = out + (size_t)t * B_SZ * H_SZ;

        f32x4 acc[2] = {};
        const _Float16* arow = hp + (size_t)(row0 + r) * H_SZ + q * 8;
#pragma unroll 8
        for (int kb = 0; kb < 64; kb++) {
            f16x8 a;
            if constexpr (CHAIN) {
                a = *(const f16x8*)(arow + kb * 32);   // plain cached load (L2 dedup)
            } else {
                union { unsigned long long u[2]; f16x8 v; } au;
                au.u[0] = __hip_atomic_load((unsigned long long*)(arow + kb * 32),
                                            __ATOMIC_RELAXED, __HIP_MEMORY_SCOPE_AGENT);
                au.u[1] = __hip_atomic_load((unsigned long long*)(arow + kb * 32) + 1,
                                            __ATOMIC_RELAXED, __HIP_MEMORY_SCOPE_AGENT);
                a = au.v;
            }
            acc[0] = __builtin_amdgcn_mfma_f32_16x16x32_f16(a, wfrag[kb * 128 + lane],      acc[0], 0, 0, 0);
            acc[1] = __builtin_amdgcn_mfma_f32_16x16x32_f16(a, wfrag[kb * 128 + 64 + lane], acc[1], 0, 0, 0);
        }

        // epilogue: tanh, fp32 out, fp16 h into LDS for coalesced coherent store
#pragma unroll
        for (int j = 0; j < 2; j++)
#pragma unroll
            for (int reg = 0; reg < 4; reg++) {
                int row = row0 + q * 4 + reg;
                int cl  = j * 16 + r;
                float v = tanhf(acc[j][reg] * W_INV_SCALE + xp[j][reg]);
                out_t[(size_t)row * H_SZ + n0 + cl] = v;
                hsl[row * 32 + cl] = (_Float16)v;
                if (t == T_STEPS - 1) final_out[(size_t)row * H_SZ + n0 + cl] = v;
            }
        __syncthreads();   // hsl complete

        // coherent h store: 64 rows x 32 cols = 512 x 8B, coalesced, write-through
        for (int idx = tid; idx < 512; idx += 256) {
            int row = idx >> 3, part = idx & 7;
            unsigned long long vv = ((const unsigned long long*)(hsl + row * 32))[part];
            __hip_atomic_store((unsigned long long*)(hn + (size_t)row * H_SZ + n0) + part,
                               vv, __ATOMIC_RELAXED, __HIP_MEMORY_SCOPE_AGENT);
        }
        if (t == T_STEPS - 1) break;

        // prefetch next step's x_proj while stores drain (h-independent)
        float* out_t1 = out_t + B_SZ * H_SZ;
#pragma unroll
        for (int j = 0; j < 2; j++)
#pragma unroll
            for (int reg = 0; reg < 4; reg++)
                xp[j][reg] = out_t1[(size_t)(row0 + q * 4 + reg) * H_SZ + n0 + j * 16 + r];

        __builtin_amdgcn_s_waitcnt(0);   // my h stores acked at coherence point
        __syncthreads();                 // all waves of block done
        if (tid == 0) {
            __hip_atomic_fetch_add(ctr, 1u, __ATOMIC_RELAXED, __HIP_MEMORY_SCOPE_AGENT);
            unsigned int target = (unsigned int)(t + 1) * NBLK;
            while (__hip_atomic_load(ctr, __ATOMIC_RELAXED, __HIP_MEMORY_SCOPE_AGENT) < target)
                __builtin_amdgcn_s_sleep(1);
        }
        __syncthreads();
    }
}

// ---------------- launcher ----------------

extern "C" void kernel_launch(void* const* d_in, const int* in_sizes, int n_in,
                              void* d_out, int out_size, void* d_ws, size_t ws_size,
                              hipStream_t stream) {
    const float* inputs = (const float*)d_in[0];   // [T,B,D]
    const float* state  = (const float*)d_in[1];   // [B,H]
    const float* W_xh   = (const float*)d_in[2];   // [D,H]
    const float* W_hh   = (const float*)d_in[3];   // [H,H]
    const float* b_h    = (const float*)d_in[4];   // [H]
    float* out = (float*)d_out;
    char* ws = (char*)d_ws;

    const size_t MB = 1ull << 20;
    // chain layout: [WxT 4MB][WhT 8MB][ctr pad 4KB][h chain: 257 x 256KB]
    // inputs_f16 (32 MB, dead after gemm) aliases chain slots h_1..h_128.
    const size_t OFF_WXT   = 0;
    const size_t OFF_WHT   = 4 * MB;
    const size_t OFF_CTR   = 12 * MB;
    const size_t OFF_CHAIN = 12 * MB + 4096;
    const size_t NEED_CHAIN = OFF_CHAIN + (size_t)(T_STEPS + 1) * HBUF * 2;

    // fallback (R4) layout
    const size_t F_IN  = 0;
    const size_t F_WXT = F_IN  + (size_t)T_STEPS * B_SZ * D_SZ * 2;
    const size_t F_WHT = F_WXT + (size_t)H_SZ * D_SZ * 2;
    const size_t F_H0  = F_WHT + (size_t)H_SZ * H_SZ * 2;
    const size_t F_H1  = F_H0  + (size_t)HBUF * 2;
    const size_t F_CTR = F_H1  + (size_t)HBUF * 2;
    const size_t NEED_PP = F_CTR + 64;

    const int n_in_el = T_STEPS * B_SZ * D_SZ;   // 16,777,216
    dim3 g1((T_STEPS * B_SZ) / 128, H_SZ / 128);
    float* final_out = out + (size_t)T_STEPS * B_SZ * H_SZ;

    if (ws_size >= NEED_CHAIN) {
        _Float16* WxT    = (_Float16*)(ws + OFF_WXT);
        _Float16* WhT    = (_Float16*)(ws + OFF_WHT);
        unsigned int* ctr = (unsigned int*)(ws + OFF_CTR);
        _Float16* hchain = (_Float16*)(ws + OFF_CHAIN);          // h_0
        _Float16* inputs_f16 = hchain + HBUF;                    // alias h_1..h_128
        _Float16* hb1 = nullptr;

        cvt_f32_f16<<<(n_in_el + 255) / 256, 256, 0, stream>>>(inputs, inputs_f16, n_in_el, 1.0f);
        transpose_to_f16<<<(D_SZ * H_SZ + 255) / 256, 256, 0, stream>>>(W_xh, WxT, D_SZ, 11, W_SCALE);
        transpose_to_f16<<<(H_SZ * H_SZ + 255) / 256, 256, 0, stream>>>(W_hh, WhT, H_SZ, 11, W_SCALE);
        cvt_f32_f16<<<(B_SZ * H_SZ + 255) / 256, 256, 0, stream>>>(state, hchain, B_SZ * H_SZ, 1.0f);
        init_ctr<<<1, 1, 0, stream>>>(ctr);

        gemm_xproj<<<g1, 256, 0, stream>>>(inputs_f16, WxT, b_h, out,
                                           T_STEPS * B_SZ, H_SZ, D_SZ);

        void* args[] = { (void*)&hchain, (void*)&hb1, (void*)&WhT,
                         (void*)&out, (void*)&final_out, (void*)&ctr };
        hipLaunchCooperativeKernel((void*)rnn_persist<true>, dim3(NBLK), dim3(256),
                                   args, 0, stream);
    } else {
        if (ws_size < NEED_PP) return;
        _Float16* inputs_f16 = (_Float16*)(ws + F_IN);
        _Float16* WxT    = (_Float16*)(ws + F_WXT);
        _Float16* WhT    = (_Float16*)(ws + F_WHT);
        _Float16* hbuf0  = (_Float16*)(ws + F_H0);
        _Float16* hbuf1  = (_Float16*)(ws + F_H1);
        unsigned int* ctr = (unsigned int*)(ws + F_CTR);

        cvt_f32_f16<<<(n_in_el + 255) / 256, 256, 0, stream>>>(inputs, inputs_f16, n_in_el, 1.0f);
        transpose_to_f16<<<(D_SZ * H_SZ + 255) / 256, 256, 0, stream>>>(W_xh, WxT, D_SZ, 11, W_SCALE);
        transpose_to_f16<<<(H_SZ * H_SZ + 255) / 256, 256, 0, stream>>>(W_hh, WhT, H_SZ, 11, W_SCALE);
        cvt_f32_f16<<<(B_SZ * H_SZ + 255) / 256, 256, 0, stream>>>(state, hbuf0, B_SZ * H_SZ, 1.0f);
        init_ctr<<<1, 1, 0, stream>>>(ctr);

        gemm_xproj<<<g1, 256, 0, stream>>>(inputs_f16, WxT, b_h, out,
                                           T_STEPS * B_SZ, H_SZ, D_SZ);

        void* args[] = { (void*)&hbuf0, (void*)&hbuf1, (void*)&WhT,
                         (void*)&out, (void*)&final_out, (void*)&ctr };
        hipLaunchCooperativeKernel((void*)rnn_persist<false>, dim3(NBLK), dim3(256),
                                   args, 0, stream);
    }
}

// Round 8
// 4009.944 us; speedup vs baseline: 1.1951x; 1.0013x over previous
//
#include <hip/hip_runtime.h>
#include <hip/hip_bf16.h>

// Problem constants: inputs [T,B,D], state [B,H], W_xh [D,H], W_hh [H,H], b_h [H]
#define T_STEPS 256
#define B_SZ    64
#define D_SZ    1024
#define H_SZ    2048
#define NBLK    64      // persistent blocks (coop-launched)
#define HBUF    (B_SZ * H_SZ)   // one h buffer: 131072 fp16 = 256 KB

// fp16 everywhere (2^-11 rounding). Weights stored x256 so all entries are
// fp16-normal (W ~ U(0,0.01)); accumulator scaled by 1/256 in epilogue.
#define W_SCALE     256.0f
#define W_INV_SCALE 0.00390625f

typedef __attribute__((ext_vector_type(8))) _Float16 f16x8;  // 8 fp16 (4 VGPRs)
typedef __attribute__((ext_vector_type(4))) float    f32x4;  // MFMA 16x16 accumulator

// ---------------- conversion kernels ----------------

__global__ void cvt_f32_f16(const float* __restrict__ in,
                            _Float16* __restrict__ out, int n, float scale) {
    int i = blockIdx.x * blockDim.x + threadIdx.x;
    if (i < n) out[i] = (_Float16)(in[i] * scale);
}

// in[rows][cols] (fp32) -> out[cols][rows] (fp16, scaled). cols = 1<<log2cols.
__global__ void transpose_to_f16(const float* __restrict__ in,
                                 _Float16* __restrict__ out,
                                 int rows, int log2cols, float scale) {
    int i = blockIdx.x * blockDim.x + threadIdx.x;
    int cols = 1 << log2cols;
    if (i >= rows * cols) return;
    int r = i >> log2cols;
    int c = i & (cols - 1);
    out[c * rows + r] = (_Float16)(in[i] * scale);
}

__global__ void init_ctr(unsigned int* ctr) { *ctr = 0u; }

// ---------------- phase 1: x_proj = inputs @ W_xh + b_h ----------------
// A [M,K] fp16 row-major, BT [N,K] fp16 (W_xh^T, x256), C [M,N] fp32.
__global__ __launch_bounds__(256) void gemm_xproj(
    const _Float16* __restrict__ A,
    const _Float16* __restrict__ BT,
    const float* __restrict__ bias,
    float* __restrict__ C,
    int M, int N, int K)
{
    int wave = threadIdx.x >> 6;
    int lane = threadIdx.x & 63;
    int q = lane >> 4;          // quad: k = q*8 + j for A/B fragments
    int r = lane & 15;          // row (A) / col (B) within 16
    int m0 = blockIdx.x * 128 + (wave >> 1) * 64;
    int n0 = blockIdx.y * 128 + (wave & 1) * 64;

    f32x4 acc[4][4] = {};
    for (int k = 0; k < K; k += 32) {
        int kk = k + q * 8;
        f16x8 a[4], b[4];
#pragma unroll
        for (int i = 0; i < 4; i++)
            a[i] = *(const f16x8*)(A + (size_t)(m0 + i * 16 + r) * K + kk);
#pragma unroll
        for (int j = 0; j < 4; j++)
            b[j] = *(const f16x8*)(BT + (size_t)(n0 + j * 16 + r) * K + kk);
#pragma unroll
        for (int i = 0; i < 4; i++)
#pragma unroll
            for (int j = 0; j < 4; j++)
                acc[i][j] = __builtin_amdgcn_mfma_f32_16x16x32_f16(a[i], b[j], acc[i][j], 0, 0, 0);
    }
#pragma unroll
    for (int i = 0; i < 4; i++)
#pragma unroll
        for (int j = 0; j < 4; j++)
#pragma unroll
            for (int reg = 0; reg < 4; reg++) {
                int row = m0 + i * 16 + q * 4 + reg;   // C/D: col=lane&15, row=(lane>>4)*4+reg
                int col = n0 + j * 16 + r;
                C[(size_t)row * N + col] = acc[i][j][reg] * W_INV_SCALE + bias[col];
            }
}

// ---------------- phase 2: persistent recurrence ----------------
// Step critical path model @2.4GHz is ~4 us, but all idle-spin variants measure
// ~14-17 us/step: consistent with DPM downclocking (~700 MHz) of a ~2%-utilized
// kernel. R6/R7: VALU-burning barrier keeps clocks up. Wave 0 (all 64 lanes,
// uniform branch) polls the global counter tight; waves 1-3 burn FMA while
// polling a monotonic LDS `go` flag. Epilogue is wave-local. R6 BUG FIXED:
// wave tile = 16 rows x 32 cols = 128 ull, 8 ull/row -> rl = u>>3, part = u&7
// (R6's u>>2/u&3 read OOB rows and stored only half the columns).
template<bool CHAIN>
__global__ __launch_bounds__(256, 1) void rnn_persist(
    _Float16* __restrict__ hbase,          // CHAIN: h_0 of chain; else ping buf
    _Float16* __restrict__ hb1,            // pong buf (fallback only)
    const _Float16* __restrict__ WT,       // [H,H] fp16 = W_hh^T x256
    float* __restrict__ out,               // [T,B,H] fp32: x_proj in, h out (in place)
    float* __restrict__ final_out,         // [B,H] fp32
    unsigned int* __restrict__ ctr)        // barrier counter (pre-zeroed)
{
    __shared__ f16x8 wfrag[8192];                        // 64 kb x 2 j x 64 lanes = 128 KB
    __shared__ __align__(16) _Float16 hsl[4][16 * 32];   // per-wave 1 KB repack
    __shared__ int go;                                   // monotonic release flag

    int tid = threadIdx.x;
    int n0 = blockIdx.x * 32;
    if (tid == 0) go = 0;

    // one-time W staging into fragment order: idx = (kb*2+j)*64 + l
    for (int idx = tid; idx < 8192; idx += 256) {
        int kb = idx >> 7, j = (idx >> 6) & 1, l = idx & 63;
        wfrag[idx] = *(const f16x8*)(WT + (size_t)(n0 + j * 16 + (l & 15)) * H_SZ
                                        + kb * 32 + (l >> 4) * 8);
    }
    __syncthreads();   // covers go=0 init too

    int wave = tid >> 6, lane = tid & 63;
    int q = lane >> 4, r = lane & 15;
    int row0 = wave * 16;                  // this wave's 16 batch rows

    // x_proj prefetch for t=0
    float xp[2][4];
#pragma unroll
    for (int j = 0; j < 2; j++)
#pragma unroll
        for (int reg = 0; reg < 4; reg++)
            xp[j][reg] = out[(size_t)(row0 + q * 4 + reg) * H_SZ + n0 + j * 16 + r];

    for (int t = 0; t < T_STEPS; t++) {
        const _Float16* hp;
        _Float16*       hn;
        if constexpr (CHAIN) {
            hp = hbase + (size_t)t * HBUF;
            hn = hbase + (size_t)(t + 1) * HBUF;
        } else {
            hp = (t & 1) ? hb1 : hbase;
            hn = (t & 1) ? hbase : hb1;
        }
        float* out_t = out + (size_t)t * B_SZ * H_SZ;

        f32x4 acc[2] = {};
        const _Float16* arow = hp + (size_t)(row0 + r) * H_SZ + q * 8;
#pragma unroll 8
        for (int kb = 0; kb < 64; kb++) {
            f16x8 a;
            if constexpr (CHAIN) {
                a = *(const f16x8*)(arow + kb * 32);   // plain cached load (fresh addr)
            } else {
                union { unsigned long long u[2]; f16x8 v; } au;
                au.u[0] = __hip_atomic_load((unsigned long long*)(arow + kb * 32),
                                            __ATOMIC_RELAXED, __HIP_MEMORY_SCOPE_AGENT);
                au.u[1] = __hip_atomic_load((unsigned long long*)(arow + kb * 32) + 1,
                                            __ATOMIC_RELAXED, __HIP_MEMORY_SCOPE_AGENT);
                a = au.v;
            }
            acc[0] = __builtin_amdgcn_mfma_f32_16x16x32_f16(a, wfrag[kb * 128 + lane],      acc[0], 0, 0, 0);
            acc[1] = __builtin_amdgcn_mfma_f32_16x16x32_f16(a, wfrag[kb * 128 + 64 + lane], acc[1], 0, 0, 0);
        }

        // wave-local epilogue: tanh, fp32 out, repack into this wave's hsl tile
#pragma unroll
        for (int j = 0; j < 2; j++)
#pragma unroll
            for (int reg = 0; reg < 4; reg++) {
                int rl = q * 4 + reg;                 // local row 0..15
                int cl = j * 16 + r;
                float v = tanhf(acc[j][reg] * W_INV_SCALE + xp[j][reg]);
                out_t[(size_t)(row0 + rl) * H_SZ + n0 + cl] = v;
                hsl[wave][rl * 32 + cl] = (_Float16)v;
                if (t == T_STEPS - 1) final_out[(size_t)(row0 + rl) * H_SZ + n0 + cl] = v;
            }
        // LDS writes complete + block compiler reordering of the punned reads
        __asm__ volatile("s_waitcnt lgkmcnt(0)" ::: "memory");

        // wave-local h store: 16 rows x 8 ull/row = 128 ull, 2 per lane.
        // u = lane + 64*s -> rl = u>>3 (0..15), part = u&7 (0..7).
#pragma unroll
        for (int s = 0; s < 2; s++) {
            int u = lane + 64 * s;
            int rl = u >> 3, part = u & 7;
            unsigned long long vv = ((const unsigned long long*)(hsl[wave] + rl * 32))[part];
            __hip_atomic_store((unsigned long long*)(hn + (size_t)(row0 + rl) * H_SZ + n0) + part,
                               vv, __ATOMIC_RELAXED, __HIP_MEMORY_SCOPE_AGENT);
        }
        if (t == T_STEPS - 1) break;

        // prefetch next step's x_proj (h-independent) while stores drain
        float* out_t1 = out_t + B_SZ * H_SZ;
#pragma unroll
        for (int j = 0; j < 2; j++)
#pragma unroll
            for (int reg = 0; reg < 4; reg++)
                xp[j][reg] = out_t1[(size_t)(row0 + q * 4 + reg) * H_SZ + n0 + j * 16 + r];

        __builtin_amdgcn_s_waitcnt(0);   // my h stores acked at coherence point
        __syncthreads();                 // block arrival: all waves' stores drained

        unsigned int target = (unsigned int)(t + 1) * NBLK;
        if (wave == 0) {
            // uniform across the wave: all lanes poll (same addr -> 1 request)
            if (lane == 0)
                __hip_atomic_fetch_add(ctr, 1u, __ATOMIC_RELAXED, __HIP_MEMORY_SCOPE_AGENT);
            while (__hip_atomic_load(ctr, __ATOMIC_RELAXED, __HIP_MEMORY_SCOPE_AGENT) < target) { }
            if (lane == 0)
                __hip_atomic_store(&go, t + 1, __ATOMIC_RELAXED, __HIP_MEMORY_SCOPE_WORKGROUP);
        } else {
            // clock keep-alive: burn VALU between LDS flag checks
            float b0 = (float)lane, b1 = 1.0000001f;
            while (__hip_atomic_load(&go, __ATOMIC_RELAXED, __HIP_MEMORY_SCOPE_WORKGROUP) < t + 1) {
#pragma unroll
                for (int z = 0; z < 32; z++)
                    b0 = __builtin_fmaf(b0, b1, 1.0e-30f);
            }
            __asm__ volatile("" :: "v"(b0));   // keep the burn alive
        }
        // no trailing syncthreads: next phase touches only wfrag(RO), global, own hsl
    }
}

// ---------------- launcher ----------------

extern "C" void kernel_launch(void* const* d_in, const int* in_sizes, int n_in,
                              void* d_out, int out_size, void* d_ws, size_t ws_size,
                              hipStream_t stream) {
    const float* inputs = (const float*)d_in[0];   // [T,B,D]
    const float* state  = (const float*)d_in[1];   // [B,H]
    const float* W_xh   = (const float*)d_in[2];   // [D,H]
    const float* W_hh   = (const float*)d_in[3];   // [H,H]
    const float* b_h    = (const float*)d_in[4];   // [H]
    float* out = (float*)d_out;
    char* ws = (char*)d_ws;

    const size_t MB = 1ull << 20;
    // chain layout: [WxT 4MB][WhT 8MB][ctr pad 4KB][h chain: 257 x 256KB]
    // inputs_f16 (32 MB, dead after gemm) aliases chain slots h_1..h_128.
    const size_t OFF_WXT   = 0;
    const size_t OFF_WHT   = 4 * MB;
    const size_t OFF_CTR   = 12 * MB;
    const size_t OFF_CHAIN = 12 * MB + 4096;
    const size_t NEED_CHAIN = OFF_CHAIN + (size_t)(T_STEPS + 1) * HBUF * 2;

    // fallback (ping-pong) layout
    const size_t F_IN  = 0;
    const size_t F_WXT = F_IN  + (size_t)T_STEPS * B_SZ * D_SZ * 2;
    const size_t F_WHT = F_WXT + (size_t)H_SZ * D_SZ * 2;
    const size_t F_H0  = F_WHT + (size_t)H_SZ * H_SZ * 2;
    const size_t F_H1  = F_H0  + (size_t)HBUF * 2;
    const size_t F_CTR = F_H1  + (size_t)HBUF * 2;
    const size_t NEED_PP = F_CTR + 64;

    const int n_in_el = T_STEPS * B_SZ * D_SZ;   // 16,777,216
    dim3 g1((T_STEPS * B_SZ) / 128, H_SZ / 128);
    float* final_out = out + (size_t)T_STEPS * B_SZ * H_SZ;

    if (ws_size >= NEED_CHAIN) {
        _Float16* WxT    = (_Float16*)(ws + OFF_WXT);
        _Float16* WhT    = (_Float16*)(ws + OFF_WHT);
        unsigned int* ctr = (unsigned int*)(ws + OFF_CTR);
        _Float16* hchain = (_Float16*)(ws + OFF_CHAIN);          // h_0
        _Float16* inputs_f16 = hchain + HBUF;                    // alias h_1..h_128
        _Float16* hb1 = nullptr;

        cvt_f32_f16<<<(n_in_el + 255) / 256, 256, 0, stream>>>(inputs, inputs_f16, n_in_el, 1.0f);
        transpose_to_f16<<<(D_SZ * H_SZ + 255) / 256, 256, 0, stream>>>(W_xh, WxT, D_SZ, 11, W_SCALE);
        transpose_to_f16<<<(H_SZ * H_SZ + 255) / 256, 256, 0, stream>>>(W_hh, WhT, H_SZ, 11, W_SCALE);
        cvt_f32_f16<<<(B_SZ * H_SZ + 255) / 256, 256, 0, stream>>>(state, hchain, B_SZ * H_SZ, 1.0f);
        init_ctr<<<1, 1, 0, stream>>>(ctr);

        gemm_xproj<<<g1, 256, 0, stream>>>(inputs_f16, WxT, b_h, out,
                                           T_STEPS * B_SZ, H_SZ, D_SZ);

        void* args[] = { (void*)&hchain, (void*)&hb1, (void*)&WhT,
                         (void*)&out, (void*)&final_out, (void*)&ctr };
        hipLaunchCooperativeKernel((void*)rnn_persist<true>, dim3(NBLK), dim3(256),
                                   args, 0, stream);
    } else {
        if (ws_size < NEED_PP) return;
        _Float16* inputs_f16 = (_Float16*)(ws + F_IN);
        _Float16* WxT    = (_Float16*)(ws + F_WXT);
        _Float16* WhT    = (_Float16*)(ws + F_WHT);
        _Float16* hbuf0  = (_Float16*)(ws + F_H0);
        _Float16* hbuf1  = (_Float16*)(ws + F_H1);
        unsigned int* ctr = (unsigned int*)(ws + F_CTR);

        cvt_f32_f16<<<(n_in_el + 255) / 256, 256, 0, stream>>>(inputs, inputs_f16, n_in_el, 1.0f);
        transpose_to_f16<<<(D_SZ * H_SZ + 255) / 256, 256, 0, stream>>>(W_xh, WxT, D_SZ, 11, W_SCALE);
        transpose_to_f16<<<(H_SZ * H_SZ + 255) / 256, 256, 0, stream>>>(W_hh, WhT, H_SZ, 11, W_SCALE);
        cvt_f32_f16<<<(B_SZ * H_SZ + 255) / 256, 256, 0, stream>>>(state, hbuf0, B_SZ * H_SZ, 1.0f);
        init_ctr<<<1, 1, 0, stream>>>(ctr);

        gemm_xproj<<<g1, 256, 0, stream>>>(inputs_f16, WxT, b_h, out,
                                           T_STEPS * B_SZ, H_SZ, D_SZ);

        void* args[] = { (void*)&hbuf0, (void*)&hbuf1, (void*)&WhT,
                         (void*)&out, (void*)&final_out, (void*)&ctr };
        hipLaunchCooperativeKernel((void*)rnn_persist<false>, dim3(NBLK), dim3(256),
                                   args, 0, stream);
    }
}

// Round 9
// 3702.842 us; speedup vs baseline: 1.2942x; 1.0829x over previous
//
#include <hip/hip_runtime.h>
#include <hip/hip_bf16.h>

// Problem constants: inputs [T,B,D], state [B,H], W_xh [D,H], W_hh [H,H], b_h [H]
#define T_STEPS 256
#define B_SZ    64
#define D_SZ    1024
#define H_SZ    2048
#define NBLK    128     // persistent blocks (coop-launched, 1/CU)
#define TPB     128     // 2 waves/block
#define HBUF    (B_SZ * H_SZ)   // one h buffer: 131072 fp16 = 256 KB

// fp16 everywhere (2^-11 rounding). Weights stored x256 so all entries are
// fp16-normal (W ~ U(0,0.01)); accumulator scaled by 1/256 in epilogue.
#define W_SCALE     256.0f
#define W_INV_SCALE 0.00390625f

typedef __attribute__((ext_vector_type(8))) _Float16 f16x8;  // 8 fp16 (4 VGPRs)
typedef __attribute__((ext_vector_type(4))) float    f32x4;  // MFMA 16x16 accumulator

// ---------------- conversion kernels ----------------

__global__ void cvt_f32_f16(const float* __restrict__ in,
                            _Float16* __restrict__ out, int n, float scale) {
    int i = blockIdx.x * blockDim.x + threadIdx.x;
    if (i < n) out[i] = (_Float16)(in[i] * scale);
}

// in[rows][cols] (fp32) -> out[cols][rows] (fp16, scaled). cols = 1<<log2cols.
__global__ void transpose_to_f16(const float* __restrict__ in,
                                 _Float16* __restrict__ out,
                                 int rows, int log2cols, float scale) {
    int i = blockIdx.x * blockDim.x + threadIdx.x;
    int cols = 1 << log2cols;
    if (i >= rows * cols) return;
    int r = i >> log2cols;
    int c = i & (cols - 1);
    out[c * rows + r] = (_Float16)(in[i] * scale);
}

// zero the barrier region: 4 arrival lines + epoch line (1024 uints = 4 KB)
__global__ void init_ctrs(unsigned int* ctr) {
    ctr[threadIdx.x + blockIdx.x * blockDim.x] = 0u;
}

// ---------------- phase 1: x_proj = inputs @ W_xh + b_h ----------------
// A [M,K] fp16 row-major, BT [N,K] fp16 (W_xh^T, x256), C [M,N] fp32.
__global__ __launch_bounds__(256) void gemm_xproj(
    const _Float16* __restrict__ A,
    const _Float16* __restrict__ BT,
    const float* __restrict__ bias,
    float* __restrict__ C,
    int M, int N, int K)
{
    int wave = threadIdx.x >> 6;
    int lane = threadIdx.x & 63;
    int q = lane >> 4;          // quad: k = q*8 + j for A/B fragments
    int r = lane & 15;          // row (A) / col (B) within 16
    int m0 = blockIdx.x * 128 + (wave >> 1) * 64;
    int n0 = blockIdx.y * 128 + (wave & 1) * 64;

    f32x4 acc[4][4] = {};
    for (int k = 0; k < K; k += 32) {
        int kk = k + q * 8;
        f16x8 a[4], b[4];
#pragma unroll
        for (int i = 0; i < 4; i++)
            a[i] = *(const f16x8*)(A + (size_t)(m0 + i * 16 + r) * K + kk);
#pragma unroll
        for (int j = 0; j < 4; j++)
            b[j] = *(const f16x8*)(BT + (size_t)(n0 + j * 16 + r) * K + kk);
#pragma unroll
        for (int i = 0; i < 4; i++)
#pragma unroll
            for (int j = 0; j < 4; j++)
                acc[i][j] = __builtin_amdgcn_mfma_f32_16x16x32_f16(a[i], b[j], acc[i][j], 0, 0, 0);
    }
#pragma unroll
    for (int i = 0; i < 4; i++)
#pragma unroll
        for (int j = 0; j < 4; j++)
#pragma unroll
            for (int reg = 0; reg < 4; reg++) {
                int row = m0 + i * 16 + q * 4 + reg;   // C/D: col=lane&15, row=(lane>>4)*4+reg
                int col = n0 + j * 16 + r;
                C[(size_t)row * N + col] = acc[i][j][reg] * W_INV_SCALE + bias[col];
            }
}

// ---------------- phase 2: persistent recurrence ----------------
// R7 evidence: burn only engaged ~15% of step -> main body (~11.5 us) is
// memory-latency bound: 64 loads/wave in unroll-8 windows = ~8 serial L2/MALL
// round trips at parked clocks. R8: (a) rotating 8-deep register prefetch ->
// one pipelined stream; (b) 128 blocks x [32 rows x 32 cols], wave = 16 rows
// full K -> per-CU h volume halves to 128 KB; (c) low-contention barrier:
// 4 spaced arrival counters + master-published epoch. h coherence as R5-R7:
// sc1 write-through stores + fresh chain addresses (plain cached reads).
template<bool CHAIN>
__global__ __launch_bounds__(TPB, 1) void rnn_persist(
    _Float16* __restrict__ hbase,          // CHAIN: h_0 of chain; else ping buf
    _Float16* __restrict__ hb1,            // pong buf (fallback only)
    const _Float16* __restrict__ WT,       // [H,H] fp16 = W_hh^T x256
    float* __restrict__ out,               // [T,B,H] fp32: x_proj in, h out (in place)
    float* __restrict__ final_out,         // [B,H] fp32
    unsigned int* __restrict__ ctr)        // barrier region (pre-zeroed 4 KB)
{
    __shared__ f16x8 wfrag[8192];                      // [kb][j][lane] = 128 KB
    __shared__ __align__(16) _Float16 hsl[2][16 * 32]; // per-wave 1 KB repack
    __shared__ int go;                                 // monotonic release flag

    int tid = threadIdx.x;
    int bid = blockIdx.x;
    int n0 = (bid >> 1) * 32;      // column range (two blocks per range)
    int rb = (bid & 1) * 32;       // row half
    if (tid == 0) go = 0;

    // one-time W staging into fragment order: idx = (kb*2+j)*64 + l
    for (int idx = tid; idx < 8192; idx += TPB) {
        int kb = idx >> 7, j = (idx >> 6) & 1, l = idx & 63;
        wfrag[idx] = *(const f16x8*)(WT + (size_t)(n0 + j * 16 + (l & 15)) * H_SZ
                                        + kb * 32 + (l >> 4) * 8);
    }
    __syncthreads();   // covers go=0 init too

    int wave = tid >> 6, lane = tid & 63;
    int q = lane >> 4, r = lane & 15;
    int row0 = rb + wave * 16;             // this wave's 16 batch rows

    unsigned int* epoch = ctr + 4 * 32;    // separate 128B line

    // x_proj prefetch for t=0
    float xp[2][4];
#pragma unroll
    for (int j = 0; j < 2; j++)
#pragma unroll
        for (int reg = 0; reg < 4; reg++)
            xp[j][reg] = out[(size_t)(row0 + q * 4 + reg) * H_SZ + n0 + j * 16 + r];

    for (int t = 0; t < T_STEPS; t++) {
        const _Float16* hp;
        _Float16*       hn;
        if constexpr (CHAIN) {
            hp = hbase + (size_t)t * HBUF;
            hn = hbase + (size_t)(t + 1) * HBUF;
        } else {
            hp = (t & 1) ? hb1 : hbase;
            hn = (t & 1) ? hbase : hb1;
        }
        float* out_t = out + (size_t)t * B_SZ * H_SZ;

        // ---- deep-pipelined A stream: rotating 8-deep prefetch, full unroll ----
        const _Float16* arow = hp + (size_t)(row0 + r) * H_SZ + q * 8;
        f16x8 abuf[8];
#pragma unroll
        for (int p = 0; p < 8; p++) {
            if constexpr (CHAIN) {
                abuf[p] = *(const f16x8*)(arow + p * 32);
            } else {
                union { unsigned long long u[2]; f16x8 v; } au;
                au.u[0] = __hip_atomic_load((unsigned long long*)(arow + p * 32),
                                            __ATOMIC_RELAXED, __HIP_MEMORY_SCOPE_AGENT);
                au.u[1] = __hip_atomic_load((unsigned long long*)(arow + p * 32) + 1,
                                            __ATOMIC_RELAXED, __HIP_MEMORY_SCOPE_AGENT);
                abuf[p] = au.v;
            }
        }
        f32x4 acc[2] = {};
#pragma unroll
        for (int kb = 0; kb < 64; kb++) {
            f16x8 a = abuf[kb & 7];
            if (kb < 56) {
                if constexpr (CHAIN) {
                    abuf[kb & 7] = *(const f16x8*)(arow + (kb + 8) * 32);
                } else {
                    union { unsigned long long u[2]; f16x8 v; } au;
                    au.u[0] = __hip_atomic_load((unsigned long long*)(arow + (kb + 8) * 32),
                                                __ATOMIC_RELAXED, __HIP_MEMORY_SCOPE_AGENT);
                    au.u[1] = __hip_atomic_load((unsigned long long*)(arow + (kb + 8) * 32) + 1,
                                                __ATOMIC_RELAXED, __HIP_MEMORY_SCOPE_AGENT);
                    abuf[kb & 7] = au.v;
                }
            }
            acc[0] = __builtin_amdgcn_mfma_f32_16x16x32_f16(a, wfrag[kb * 128 + lane],      acc[0], 0, 0, 0);
            acc[1] = __builtin_amdgcn_mfma_f32_16x16x32_f16(a, wfrag[kb * 128 + 64 + lane], acc[1], 0, 0, 0);
        }

        // wave-local epilogue: tanh, fp32 out, repack into this wave's hsl tile
#pragma unroll
        for (int j = 0; j < 2; j++)
#pragma unroll
            for (int reg = 0; reg < 4; reg++) {
                int rl = q * 4 + reg;                 // local row 0..15
                int cl = j * 16 + r;
                float v = tanhf(acc[j][reg] * W_INV_SCALE + xp[j][reg]);
                out_t[(size_t)(row0 + rl) * H_SZ + n0 + cl] = v;
                hsl[wave][rl * 32 + cl] = (_Float16)v;
                if (t == T_STEPS - 1) final_out[(size_t)(row0 + rl) * H_SZ + n0 + cl] = v;
            }
        // LDS writes complete + block compiler reordering of the punned reads
        __asm__ volatile("s_waitcnt lgkmcnt(0)" ::: "memory");

        // wave-local h store: 16 rows x 8 ull/row = 128 ull, 2 per lane
#pragma unroll
        for (int s = 0; s < 2; s++) {
            int u = lane + 64 * s;
            int rl = u >> 3, part = u & 7;
            unsigned long long vv = ((const unsigned long long*)(hsl[wave] + rl * 32))[part];
            __hip_atomic_store((unsigned long long*)(hn + (size_t)(row0 + rl) * H_SZ + n0) + part,
                               vv, __ATOMIC_RELAXED, __HIP_MEMORY_SCOPE_AGENT);
        }
        if (t == T_STEPS - 1) break;

        // prefetch next step's x_proj (h-independent) while stores drain
        float* out_t1 = out_t + B_SZ * H_SZ;
#pragma unroll
        for (int j = 0; j < 2; j++)
#pragma unroll
            for (int reg = 0; reg < 4; reg++)
                xp[j][reg] = out_t1[(size_t)(row0 + q * 4 + reg) * H_SZ + n0 + j * 16 + r];

        __builtin_amdgcn_s_waitcnt(0);   // h stores acked at coherence point
        __syncthreads();                 // block arrival: both waves drained

        unsigned int tgt = (unsigned int)(t + 1);
        if (wave == 0) {
            if (lane == 0)
                __hip_atomic_fetch_add(ctr + (bid & 3) * 32, 1u,
                                       __ATOMIC_RELAXED, __HIP_MEMORY_SCOPE_AGENT);
            if (bid == 0) {
                // master: all lanes poll the 4 arrival lines in one load
                unsigned int line_tgt = tgt * (NBLK / 4);
                for (;;) {
                    unsigned int v = __hip_atomic_load(ctr + (lane & 3) * 32,
                                                       __ATOMIC_RELAXED, __HIP_MEMORY_SCOPE_AGENT);
                    if (__ballot(v < line_tgt) == 0ull) break;
                }
                if (lane == 0)
                    __hip_atomic_store(epoch, tgt, __ATOMIC_RELAXED, __HIP_MEMORY_SCOPE_AGENT);
            } else {
                while (__hip_atomic_load(epoch, __ATOMIC_RELAXED, __HIP_MEMORY_SCOPE_AGENT) < tgt) { }
            }
            if (lane == 0)
                __hip_atomic_store(&go, (int)tgt, __ATOMIC_RELAXED, __HIP_MEMORY_SCOPE_WORKGROUP);
        } else {
            // clock keep-alive: burn VALU between LDS flag checks
            float b0 = (float)lane, b1 = 1.0000001f;
            while (__hip_atomic_load(&go, __ATOMIC_RELAXED, __HIP_MEMORY_SCOPE_WORKGROUP) < (int)tgt) {
#pragma unroll
                for (int z = 0; z < 32; z++)
                    b0 = __builtin_fmaf(b0, b1, 1.0e-30f);
            }
            __asm__ volatile("" :: "v"(b0));
        }
        // no trailing syncthreads: next phase touches only wfrag(RO), global, own hsl
    }
}

// ---------------- launcher ----------------

extern "C" void kernel_launch(void* const* d_in, const int* in_sizes, int n_in,
                              void* d_out, int out_size, void* d_ws, size_t ws_size,
                              hipStream_t stream) {
    const float* inputs = (const float*)d_in[0];   // [T,B,D]
    const float* state  = (const float*)d_in[1];   // [B,H]
    const float* W_xh   = (const float*)d_in[2];   // [D,H]
    const float* W_hh   = (const float*)d_in[3];   // [H,H]
    const float* b_h    = (const float*)d_in[4];   // [H]
    float* out = (float*)d_out;
    char* ws = (char*)d_ws;

    const size_t MB = 1ull << 20;
    // chain layout: [WxT 4MB][WhT 8MB][ctr 8KB][h chain: 257 x 256KB]
    // inputs_f16 (32 MB, dead after gemm) aliases chain slots h_1..h_128.
    const size_t OFF_WXT   = 0;
    const size_t OFF_WHT   = 4 * MB;
    const size_t OFF_CTR   = 12 * MB;
    const size_t OFF_CHAIN = 12 * MB + 8192;
    const size_t NEED_CHAIN = OFF_CHAIN + (size_t)(T_STEPS + 1) * HBUF * 2;

    // fallback (ping-pong) layout
    const size_t F_IN  = 0;
    const size_t F_WXT = F_IN  + (size_t)T_STEPS * B_SZ * D_SZ * 2;
    const size_t F_WHT = F_WXT + (size_t)H_SZ * D_SZ * 2;
    const size_t F_H0  = F_WHT + (size_t)H_SZ * H_SZ * 2;
    const size_t F_H1  = F_H0  + (size_t)HBUF * 2;
    const size_t F_CTR = F_H1  + (size_t)HBUF * 2;
    const size_t NEED_PP = F_CTR + 4096;

    const int n_in_el = T_STEPS * B_SZ * D_SZ;   // 16,777,216
    dim3 g1((T_STEPS * B_SZ) / 128, H_SZ / 128);
    float* final_out = out + (size_t)T_STEPS * B_SZ * H_SZ;

    if (ws_size >= NEED_CHAIN) {
        _Float16* WxT    = (_Float16*)(ws + OFF_WXT);
        _Float16* WhT    = (_Float16*)(ws + OFF_WHT);
        unsigned int* ctr = (unsigned int*)(ws + OFF_CTR);
        _Float16* hchain = (_Float16*)(ws + OFF_CHAIN);          // h_0
        _Float16* inputs_f16 = hchain + HBUF;                    // alias h_1..h_128
        _Float16* hb1 = nullptr;

        cvt_f32_f16<<<(n_in_el + 255) / 256, 256, 0, stream>>>(inputs, inputs_f16, n_in_el, 1.0f);
        transpose_to_f16<<<(D_SZ * H_SZ + 255) / 256, 256, 0, stream>>>(W_xh, WxT, D_SZ, 11, W_SCALE);
        transpose_to_f16<<<(H_SZ * H_SZ + 255) / 256, 256, 0, stream>>>(W_hh, WhT, H_SZ, 11, W_SCALE);
        cvt_f32_f16<<<(B_SZ * H_SZ + 255) / 256, 256, 0, stream>>>(state, hchain, B_SZ * H_SZ, 1.0f);
        init_ctrs<<<4, 256, 0, stream>>>(ctr);   // zero 4 KB barrier region

        gemm_xproj<<<g1, 256, 0, stream>>>(inputs_f16, WxT, b_h, out,
                                           T_STEPS * B_SZ, H_SZ, D_SZ);

        void* args[] = { (void*)&hchain, (void*)&hb1, (void*)&WhT,
                         (void*)&out, (void*)&final_out, (void*)&ctr };
        hipLaunchCooperativeKernel((void*)rnn_persist<true>, dim3(NBLK), dim3(TPB),
                                   args, 0, stream);
    } else {
        if (ws_size < NEED_PP) return;
        _Float16* inputs_f16 = (_Float16*)(ws + F_IN);
        _Float16* WxT    = (_Float16*)(ws + F_WXT);
        _Float16* WhT    = (_Float16*)(ws + F_WHT);
        _Float16* hbuf0  = (_Float16*)(ws + F_H0);
        _Float16* hbuf1  = (_Float16*)(ws + F_H1);
        unsigned int* ctr = (unsigned int*)(ws + F_CTR);

        cvt_f32_f16<<<(n_in_el + 255) / 256, 256, 0, stream>>>(inputs, inputs_f16, n_in_el, 1.0f);
        transpose_to_f16<<<(D_SZ * H_SZ + 255) / 256, 256, 0, stream>>>(W_xh, WxT, D_SZ, 11, W_SCALE);
        transpose_to_f16<<<(H_SZ * H_SZ + 255) / 256, 256, 0, stream>>>(W_hh, WhT, H_SZ, 11, W_SCALE);
        cvt_f32_f16<<<(B_SZ * H_SZ + 255) / 256, 256, 0, stream>>>(state, hbuf0, B_SZ * H_SZ, 1.0f);
        init_ctrs<<<4, 256, 0, stream>>>(ctr);

        gemm_xproj<<<g1, 256, 0, stream>>>(inputs_f16, WxT, b_h, out,
                                           T_STEPS * B_SZ, H_SZ, D_SZ);

        void* args[] = { (void*)&hbuf0, (void*)&hbuf1, (void*)&WhT,
                         (void*)&out, (void*)&final_out, (void*)&ctr };
        hipLaunchCooperativeKernel((void*)rnn_persist<false>, dim3(NBLK), dim3(TPB),
                                   args, 0, stream);
    }
}

// Round 10
// 2373.432 us; speedup vs baseline: 2.0191x; 1.5601x over previous
//
#include <hip/hip_runtime.h>
#include <hip/hip_bf16.h>

// Problem constants: inputs [T,B,D], state [B,H], W_xh [D,H], W_hh [H,H], b_h [H]
#define T_STEPS 256
#define B_SZ    64
#define D_SZ    1024
#define H_SZ    2048
#define NBLK    256     // persistent blocks, 1/CU (coop-launched)
#define TPB     192     // wave0,1 = compute; wave2 = clock-burn
#define HBUF    (B_SZ * H_SZ)   // one h buffer: 131072 fp16 = 256 KB

// fp16 everywhere (2^-11 rounding). Weights stored x256 so all entries are
// fp16-normal (W ~ U(0,0.01)); accumulator scaled by 1/256 in epilogue.
#define W_SCALE     256.0f
#define W_INV_SCALE 0.00390625f

typedef __attribute__((ext_vector_type(8))) _Float16 f16x8;  // 8 fp16 (4 VGPRs)
typedef __attribute__((ext_vector_type(4))) float    f32x4;  // MFMA 16x16 accumulator

// ---------------- conversion kernels ----------------

__global__ void cvt_f32_f16(const float* __restrict__ in,
                            _Float16* __restrict__ out, int n, float scale) {
    int i = blockIdx.x * blockDim.x + threadIdx.x;
    if (i < n) out[i] = (_Float16)(in[i] * scale);
}

// in[rows][cols] (fp32) -> out[cols][rows] (fp16, scaled). cols = 1<<log2cols.
__global__ void transpose_to_f16(const float* __restrict__ in,
                                 _Float16* __restrict__ out,
                                 int rows, int log2cols, float scale) {
    int i = blockIdx.x * blockDim.x + threadIdx.x;
    int cols = 1 << log2cols;
    if (i >= rows * cols) return;
    int r = i >> log2cols;
    int c = i & (cols - 1);
    out[c * rows + r] = (_Float16)(in[i] * scale);
}

// zero the barrier region (12 used lines; zero 4 KB)
__global__ void init_ctrs(unsigned int* ctr) {
    ctr[threadIdx.x + blockIdx.x * blockDim.x] = 0u;
}

// ---------------- phase 1: x_proj = inputs @ W_xh + b_h ----------------
__global__ __launch_bounds__(256) void gemm_xproj(
    const _Float16* __restrict__ A,
    const _Float16* __restrict__ BT,
    const float* __restrict__ bias,
    float* __restrict__ C,
    int M, int N, int K)
{
    int wave = threadIdx.x >> 6;
    int lane = threadIdx.x & 63;
    int q = lane >> 4;
    int r = lane & 15;
    int m0 = blockIdx.x * 128 + (wave >> 1) * 64;
    int n0 = blockIdx.y * 128 + (wave & 1) * 64;

    f32x4 acc[4][4] = {};
    for (int k = 0; k < K; k += 32) {
        int kk = k + q * 8;
        f16x8 a[4], b[4];
#pragma unroll
        for (int i = 0; i < 4; i++)
            a[i] = *(const f16x8*)(A + (size_t)(m0 + i * 16 + r) * K + kk);
#pragma unroll
        for (int j = 0; j < 4; j++)
            b[j] = *(const f16x8*)(BT + (size_t)(n0 + j * 16 + r) * K + kk);
#pragma unroll
        for (int i = 0; i < 4; i++)
#pragma unroll
            for (int j = 0; j < 4; j++)
                acc[i][j] = __builtin_amdgcn_mfma_f32_16x16x32_f16(a[i], b[j], acc[i][j], 0, 0, 0);
    }
#pragma unroll
    for (int i = 0; i < 4; i++)
#pragma unroll
        for (int j = 0; j < 4; j++)
#pragma unroll
            for (int reg = 0; reg < 4; reg++) {
                int row = m0 + i * 16 + q * 4 + reg;   // C/D: col=lane&15, row=(lane>>4)*4+reg
                int col = n0 + j * 16 + r;
                C[(size_t)row * N + col] = acc[i][j][reg] * W_INV_SCALE + bias[col];
            }
}

// ---------------- phase 2: persistent recurrence ----------------
// R8 model: step is latency x in-flight bound at DPM-parked clocks (~4 us
// @2.4GHz chain measured as ~12.6 us). R9: (1) dedicated burn wave keeps
// SCLK up (clean clock experiment); (2) 256 blocks of [16 rows x 32 cols],
// wave = 16-col half x full K, 16-deep prefetch (2x in-flight, 1/2 per-CU
// volume); (3) dependency decomposition: block (c,g) reads only rows of its
// own row-group g -> 4 independent 64-block barriers (fan-in/jitter 4x down).
// h coherence as R5-R8: sc1 write-through stores + fresh chain addresses.
// NOTE: no __syncthreads after the burn wave diverges -- all in-loop syncs
// are LDS-flag handshakes between the two compute waves.
template<bool CHAIN>
__global__ __launch_bounds__(TPB, 1) void rnn_persist(
    _Float16* __restrict__ hbase,          // CHAIN: h_0 of chain; else ping buf
    _Float16* __restrict__ hb1,            // pong buf (fallback only)
    const _Float16* __restrict__ WT,       // [H,H] fp16 = W_hh^T x256
    float* __restrict__ out,               // [T,B,H] fp32: x_proj in, h out (in place)
    float* __restrict__ final_out,         // [B,H] fp32
    unsigned int* __restrict__ ctr)        // barrier region (pre-zeroed)
{
    __shared__ f16x8 wfrag[8192];                   // [kb][j][lane] = 128 KB
    __shared__ __align__(16) _Float16 hsl[16 * 32]; // 1 KB block h tile
    __shared__ int go, hfl0, hfl1, w1done;          // monotonic flags

    int tid = threadIdx.x;
    int bid = blockIdx.x;
    int g   = (bid >> 1) & 3;                    // row group (XCD-pair under round-robin)
    int c   = ((bid >> 3) << 1) | (bid & 1);     // col range 0..63
    int n0  = c * 32;
    int row0 = g * 16;                           // block's 16 batch rows

    if (tid == 0) { go = 0; hfl0 = 0; hfl1 = 0; w1done = 0; }

    // one-time W staging into fragment order: idx = (kb*2+j)*64 + l
    for (int idx = tid; idx < 8192; idx += TPB) {
        int kb = idx >> 7, j = (idx >> 6) & 1, l = idx & 63;
        wfrag[idx] = *(const f16x8*)(WT + (size_t)(n0 + j * 16 + (l & 15)) * H_SZ
                                        + kb * 32 + (l >> 4) * 8);
    }
    __syncthreads();   // the ONLY block-wide barrier (covers flag init)

    int wave = tid >> 6, lane = tid & 63;

    if (wave == 2) {
        // dedicated clock keep-alive: 4 independent FMA chains, poll LDS exit flag
        float c0 = 1.0f + lane, c1 = 2.0f, c2 = 3.0f, c3 = 4.0f;
        const float k1 = 1.0000001f, k2 = 1.0e-30f;
        while (__hip_atomic_load(&go, __ATOMIC_RELAXED, __HIP_MEMORY_SCOPE_WORKGROUP) < T_STEPS) {
#pragma unroll
            for (int z = 0; z < 64; z++) {
                c0 = __builtin_fmaf(c0, k1, k2);
                c1 = __builtin_fmaf(c1, k1, k2);
                c2 = __builtin_fmaf(c2, k1, k2);
                c3 = __builtin_fmaf(c3, k1, k2);
            }
        }
        __asm__ volatile("" :: "v"(c0), "v"(c1), "v"(c2), "v"(c3));
        return;
    }

    int q = lane >> 4, r = lane & 15;
    int w16 = wave * 16;                         // this wave's 16-col half
    int* myh = wave ? &hfl1 : &hfl0;
    int* oth = wave ? &hfl0 : &hfl1;

    unsigned int* aline = ctr + (g * 2 + (bid & 1)) * 32;   // group arrival line
    unsigned int* epoch = ctr + (8 + g) * 32;               // group epoch line
    bool master = (bid == 2 * g);                // one master per group (bid<8, even)

    // x_proj prefetch for t=0
    float xp[4];
#pragma unroll
    for (int reg = 0; reg < 4; reg++)
        xp[reg] = out[(size_t)(row0 + q * 4 + reg) * H_SZ + n0 + w16 + r];

    for (int t = 0; t < T_STEPS; t++) {
        const _Float16* hp;
        _Float16*       hn;
        if constexpr (CHAIN) {
            hp = hbase + (size_t)t * HBUF;
            hn = hbase + (size_t)(t + 1) * HBUF;
        } else {
            hp = (t & 1) ? hb1 : hbase;
            hn = (t & 1) ? hbase : hb1;
        }
        float* out_t = out + (size_t)t * B_SZ * H_SZ;

        // ---- A stream: 16-deep rotating prefetch, fully unrolled ----
        const _Float16* arow = hp + (size_t)(row0 + r) * H_SZ + q * 8;
        f16x8 abuf[16];
#pragma unroll
        for (int p = 0; p < 16; p++) {
            if constexpr (CHAIN) {
                abuf[p] = *(const f16x8*)(arow + p * 32);
            } else {
                union { unsigned long long u[2]; f16x8 v; } au;
                au.u[0] = __hip_atomic_load((unsigned long long*)(arow + p * 32),
                                            __ATOMIC_RELAXED, __HIP_MEMORY_SCOPE_AGENT);
                au.u[1] = __hip_atomic_load((unsigned long long*)(arow + p * 32) + 1,
                                            __ATOMIC_RELAXED, __HIP_MEMORY_SCOPE_AGENT);
                abuf[p] = au.v;
            }
        }
        f32x4 acc = {};
#pragma unroll
        for (int kb = 0; kb < 64; kb++) {
            f16x8 a = abuf[kb & 15];
            if (kb < 48) {
                if constexpr (CHAIN) {
                    abuf[kb & 15] = *(const f16x8*)(arow + (kb + 16) * 32);
                } else {
                    union { unsigned long long u[2]; f16x8 v; } au;
                    au.u[0] = __hip_atomic_load((unsigned long long*)(arow + (kb + 16) * 32),
                                                __ATOMIC_RELAXED, __HIP_MEMORY_SCOPE_AGENT);
                    au.u[1] = __hip_atomic_load((unsigned long long*)(arow + (kb + 16) * 32) + 1,
                                                __ATOMIC_RELAXED, __HIP_MEMORY_SCOPE_AGENT);
                    abuf[kb & 15] = au.v;
                }
            }
            acc = __builtin_amdgcn_mfma_f32_16x16x32_f16(a, wfrag[kb * 128 + wave * 64 + lane],
                                                         acc, 0, 0, 0);
        }

        // epilogue: tanh, fp32 out, pack h half-tile into hsl
#pragma unroll
        for (int reg = 0; reg < 4; reg++) {
            int rl = q * 4 + reg;                       // local row 0..15
            float v = tanhf(acc[reg] * W_INV_SCALE + xp[reg]);
            out_t[(size_t)(row0 + rl) * H_SZ + n0 + w16 + r] = v;
            hsl[rl * 32 + w16 + r] = (_Float16)v;
            if (t == T_STEPS - 1) final_out[(size_t)(row0 + rl) * H_SZ + n0 + w16 + r] = v;
        }
        if (t == T_STEPS - 1) {
            if (wave == 0 && lane == 0)
                __hip_atomic_store(&go, T_STEPS, __ATOMIC_RELAXED, __HIP_MEMORY_SCOPE_WORKGROUP);
            break;
        }

        // pair handshake: both halves of hsl complete before the row-split store
        __asm__ volatile("s_waitcnt lgkmcnt(0)" ::: "memory");
        int tg = t + 1;
        if (lane == 0)
            __hip_atomic_store(myh, tg, __ATOMIC_RELAXED, __HIP_MEMORY_SCOPE_WORKGROUP);
        while (__hip_atomic_load(oth, __ATOMIC_RELAXED, __HIP_MEMORY_SCOPE_WORKGROUP) < tg) { }
        __asm__ volatile("" ::: "memory");

        // h store: wave w stores rows [w*8, w*8+8) x 32 cols = 64 ull, 1/lane
        {
            int rl = wave * 8 + (lane >> 3), part = lane & 7;
            unsigned long long vv = ((const unsigned long long*)hsl)[rl * 8 + part];
            __hip_atomic_store((unsigned long long*)(hn + (size_t)(row0 + rl) * H_SZ + n0) + part,
                               vv, __ATOMIC_RELAXED, __HIP_MEMORY_SCOPE_AGENT);
        }

        // prefetch next step's x_proj (h-independent) while stores drain
        float* out_t1 = out_t + B_SZ * H_SZ;
#pragma unroll
        for (int reg = 0; reg < 4; reg++)
            xp[reg] = out_t1[(size_t)(row0 + q * 4 + reg) * H_SZ + n0 + w16 + r];

        __builtin_amdgcn_s_waitcnt(0);   // h stores acked at coherence point

        if (wave == 1) {
            if (lane == 0)
                __hip_atomic_store(&w1done, tg, __ATOMIC_RELAXED, __HIP_MEMORY_SCOPE_WORKGROUP);
            while (__hip_atomic_load(&go, __ATOMIC_RELAXED, __HIP_MEMORY_SCOPE_WORKGROUP) < tg) { }
        } else {
            while (__hip_atomic_load(&w1done, __ATOMIC_RELAXED, __HIP_MEMORY_SCOPE_WORKGROUP) < tg) { }
            if (lane == 0)
                __hip_atomic_fetch_add(aline, 1u, __ATOMIC_RELAXED, __HIP_MEMORY_SCOPE_AGENT);
            if (master) {
                unsigned int line_tgt = (unsigned int)tg * 32u;
                for (;;) {
                    unsigned int v = __hip_atomic_load(ctr + (g * 2 + (lane & 1)) * 32,
                                                       __ATOMIC_RELAXED, __HIP_MEMORY_SCOPE_AGENT);
                    if (__ballot(v < line_tgt) == 0ull) break;
                }
                if (lane == 0)
                    __hip_atomic_store(epoch, (unsigned int)tg,
                                       __ATOMIC_RELAXED, __HIP_MEMORY_SCOPE_AGENT);
            } else {
                while (__hip_atomic_load(epoch, __ATOMIC_RELAXED, __HIP_MEMORY_SCOPE_AGENT)
                       < (unsigned int)tg) { }
            }
            if (lane == 0)
                __hip_atomic_store(&go, tg, __ATOMIC_RELAXED, __HIP_MEMORY_SCOPE_WORKGROUP);
        }
    }
}

// ---------------- launcher ----------------

extern "C" void kernel_launch(void* const* d_in, const int* in_sizes, int n_in,
                              void* d_out, int out_size, void* d_ws, size_t ws_size,
                              hipStream_t stream) {
    const float* inputs = (const float*)d_in[0];   // [T,B,D]
    const float* state  = (const float*)d_in[1];   // [B,H]
    const float* W_xh   = (const float*)d_in[2];   // [D,H]
    const float* W_hh   = (const float*)d_in[3];   // [H,H]
    const float* b_h    = (const float*)d_in[4];   // [H]
    float* out = (float*)d_out;
    char* ws = (char*)d_ws;

    const size_t MB = 1ull << 20;
    // chain layout: [WxT 4MB][WhT 8MB][ctr 8KB][h chain: 257 x 256KB]
    // inputs_f16 (32 MB, dead after gemm) aliases chain slots h_1..h_128.
    const size_t OFF_WXT   = 0;
    const size_t OFF_WHT   = 4 * MB;
    const size_t OFF_CTR   = 12 * MB;
    const size_t OFF_CHAIN = 12 * MB + 8192;
    const size_t NEED_CHAIN = OFF_CHAIN + (size_t)(T_STEPS + 1) * HBUF * 2;

    // fallback (ping-pong) layout
    const size_t F_IN  = 0;
    const size_t F_WXT = F_IN  + (size_t)T_STEPS * B_SZ * D_SZ * 2;
    const size_t F_WHT = F_WXT + (size_t)H_SZ * D_SZ * 2;
    const size_t F_H0  = F_WHT + (size_t)H_SZ * H_SZ * 2;
    const size_t F_H1  = F_H0  + (size_t)HBUF * 2;
    const size_t F_CTR = F_H1  + (size_t)HBUF * 2;
    const size_t NEED_PP = F_CTR + 4096;

    const int n_in_el = T_STEPS * B_SZ * D_SZ;   // 16,777,216
    dim3 g1((T_STEPS * B_SZ) / 128, H_SZ / 128);
    float* final_out = out + (size_t)T_STEPS * B_SZ * H_SZ;

    if (ws_size >= NEED_CHAIN) {
        _Float16* WxT    = (_Float16*)(ws + OFF_WXT);
        _Float16* WhT    = (_Float16*)(ws + OFF_WHT);
        unsigned int* ctr = (unsigned int*)(ws + OFF_CTR);
        _Float16* hchain = (_Float16*)(ws + OFF_CHAIN);          // h_0
        _Float16* inputs_f16 = hchain + HBUF;                    // alias h_1..h_128
        _Float16* hb1 = nullptr;

        cvt_f32_f16<<<(n_in_el + 255) / 256, 256, 0, stream>>>(inputs, inputs_f16, n_in_el, 1.0f);
        transpose_to_f16<<<(D_SZ * H_SZ + 255) / 256, 256, 0, stream>>>(W_xh, WxT, D_SZ, 11, W_SCALE);
        transpose_to_f16<<<(H_SZ * H_SZ + 255) / 256, 256, 0, stream>>>(W_hh, WhT, H_SZ, 11, W_SCALE);
        cvt_f32_f16<<<(B_SZ * H_SZ + 255) / 256, 256, 0, stream>>>(state, hchain, B_SZ * H_SZ, 1.0f);
        init_ctrs<<<4, 256, 0, stream>>>(ctr);

        gemm_xproj<<<g1, 256, 0, stream>>>(inputs_f16, WxT, b_h, out,
                                           T_STEPS * B_SZ, H_SZ, D_SZ);

        void* args[] = { (void*)&hchain, (void*)&hb1, (void*)&WhT,
                         (void*)&out, (void*)&final_out, (void*)&ctr };
        hipLaunchCooperativeKernel((void*)rnn_persist<true>, dim3(NBLK), dim3(TPB),
                                   args, 0, stream);
    } else {
        if (ws_size < NEED_PP) return;
        _Float16* inputs_f16 = (_Float16*)(ws + F_IN);
        _Float16* WxT    = (_Float16*)(ws + F_WXT);
        _Float16* WhT    = (_Float16*)(ws + F_WHT);
        _Float16* hbuf0  = (_Float16*)(ws + F_H0);
        _Float16* hbuf1  = (_Float16*)(ws + F_H1);
        unsigned int* ctr = (unsigned int*)(ws + F_CTR);

        cvt_f32_f16<<<(n_in_el + 255) / 256, 256, 0, stream>>>(inputs, inputs_f16, n_in_el, 1.0f);
        transpose_to_f16<<<(D_SZ * H_SZ + 255) / 256, 256, 0, stream>>>(W_xh, WxT, D_SZ, 11, W_SCALE);
        transpose_to_f16<<<(H_SZ * H_SZ + 255) / 256, 256, 0, stream>>>(W_hh, WhT, H_SZ, 11, W_SCALE);
        cvt_f32_f16<<<(B_SZ * H_SZ + 255) / 256, 256, 0, stream>>>(state, hbuf0, B_SZ * H_SZ, 1.0f);
        init_ctrs<<<4, 256, 0, stream>>>(ctr);

        gemm_xproj<<<g1, 256, 0, stream>>>(inputs_f16, WxT, b_h, out,
                                           T_STEPS * B_SZ, H_SZ, D_SZ);

        void* args[] = { (void*)&hbuf0, (void*)&hbuf1, (void*)&WhT,
                         (void*)&out, (void*)&final_out, (void*)&ctr };
        hipLaunchCooperativeKernel((void*)rnn_persist<false>, dim3(NBLK), dim3(TPB),
                                   args, 0, stream);
    }
}

// Round 11
// 1808.852 us; speedup vs baseline: 2.6493x; 1.3121x over previous
//
#include <hip/hip_runtime.h>
#include <hip/hip_bf16.h>

// Problem constants: inputs [T,B,D], state [B,H], W_xh [D,H], W_hh [H,H], b_h [H]
#define T_STEPS 256
#define B_SZ    64
#define D_SZ    1024
#define H_SZ    2048
#define NBLK    256     // persistent blocks, 1/CU (coop-launched)
#define TPB     320     // waves 0-3 = compute (K-split), wave 4 = clock-burn
#define HBUF    (B_SZ * H_SZ)   // one h buffer: 131072 fp16 = 256 KB

// fp16 everywhere (2^-11 rounding). Weights stored x256 so all entries are
// fp16-normal (W ~ U(0,0.01)); accumulator scaled by 1/256 in epilogue.
#define W_SCALE     256.0f
#define W_INV_SCALE 0.00390625f

typedef __attribute__((ext_vector_type(8))) _Float16 f16x8;  // 8 fp16 (4 VGPRs)
typedef __attribute__((ext_vector_type(4))) float    f32x4;  // MFMA 16x16 accumulator

// ---------------- conversion kernels ----------------

__global__ void cvt_f32_f16(const float* __restrict__ in,
                            _Float16* __restrict__ out, int n, float scale) {
    int i = blockIdx.x * blockDim.x + threadIdx.x;
    if (i < n) out[i] = (_Float16)(in[i] * scale);
}

__global__ void transpose_to_f16(const float* __restrict__ in,
                                 _Float16* __restrict__ out,
                                 int rows, int log2cols, float scale) {
    int i = blockIdx.x * blockDim.x + threadIdx.x;
    int cols = 1 << log2cols;
    if (i >= rows * cols) return;
    int r = i >> log2cols;
    int c = i & (cols - 1);
    out[c * rows + r] = (_Float16)(in[i] * scale);
}

__global__ void init_ctrs(unsigned int* ctr) {
    ctr[threadIdx.x + blockIdx.x * blockDim.x] = 0u;
}

// ---------------- phase 1: x_proj = inputs @ W_xh + b_h ----------------
__global__ __launch_bounds__(256) void gemm_xproj(
    const _Float16* __restrict__ A,
    const _Float16* __restrict__ BT,
    const float* __restrict__ bias,
    float* __restrict__ C,
    int M, int N, int K)
{
    int wave = threadIdx.x >> 6;
    int lane = threadIdx.x & 63;
    int q = lane >> 4;
    int r = lane & 15;
    int m0 = blockIdx.x * 128 + (wave >> 1) * 64;
    int n0 = blockIdx.y * 128 + (wave & 1) * 64;

    f32x4 acc[4][4] = {};
    for (int k = 0; k < K; k += 32) {
        int kk = k + q * 8;
        f16x8 a[4], b[4];
#pragma unroll
        for (int i = 0; i < 4; i++)
            a[i] = *(const f16x8*)(A + (size_t)(m0 + i * 16 + r) * K + kk);
#pragma unroll
        for (int j = 0; j < 4; j++)
            b[j] = *(const f16x8*)(BT + (size_t)(n0 + j * 16 + r) * K + kk);
#pragma unroll
        for (int i = 0; i < 4; i++)
#pragma unroll
            for (int j = 0; j < 4; j++)
                acc[i][j] = __builtin_amdgcn_mfma_f32_16x16x32_f16(a[i], b[j], acc[i][j], 0, 0, 0);
    }
#pragma unroll
    for (int i = 0; i < 4; i++)
#pragma unroll
        for (int j = 0; j < 4; j++)
#pragma unroll
            for (int reg = 0; reg < 4; reg++) {
                int row = m0 + i * 16 + q * 4 + reg;   // C/D: col=lane&15, row=(lane>>4)*4+reg
                int col = n0 + j * 16 + r;
                C[(size_t)row * N + col] = acc[i][j][reg] * W_INV_SCALE + bias[col];
            }
}

// ---------------- phase 2: persistent recurrence ----------------
// R9 residual (7.6 us/step): A-stream = 4 serial MALL windows + multi-hop
// barrier, at partially-parked clock. R10: (1) K split across 4 compute waves
// (512 each) -> 16 loads all in flight = ONE latency window; LDS partial
// reduce by waves 0/1; (2) flat barrier: every block's wave0 adds to its
// group parity line and polls both lines directly (no master/epoch hops);
// (3) reducer waves own tanh/out/h-store for their column half (wave-local).
// Dependency decomposition retained: block group g (16 rows) has its own
// 64-block barrier on its own 2 lines. h coherence: sc1 write-through stores
// + fresh chain addresses (plain cached reads). Burn wave = wave 4.
template<bool CHAIN>
__global__ __launch_bounds__(TPB, 1) void rnn_persist(
    _Float16* __restrict__ hbase,          // CHAIN: h_0 of chain; else ping buf
    _Float16* __restrict__ hb1,            // pong buf (fallback only)
    const _Float16* __restrict__ WT,       // [H,H] fp16 = W_hh^T x256
    float* __restrict__ out,               // [T,B,H] fp32: x_proj in, h out (in place)
    float* __restrict__ final_out,         // [B,H] fp32
    unsigned int* __restrict__ ctr)        // barrier region (pre-zeroed)
{
    __shared__ f16x8 wfrag[8192];                   // [kb][half][lane] = 128 KB
    __shared__ float part[4][2][256];               // [w][half][lane*4+reg] = 8 KB
    __shared__ __align__(16) _Float16 hsl[16 * 32]; // 1 KB block h tile
    __shared__ int pdone[4];                        // per-wave partial flags
    __shared__ int hdone1, go;                      // monotonic flags

    int tid = threadIdx.x;
    int bid = blockIdx.x;
    int g   = (bid >> 1) & 3;                    // row group (XCD-pair under round-robin)
    int c   = ((bid >> 3) << 1) | (bid & 1);     // col range 0..63
    int n0  = c * 32;
    int row0 = g * 16;                           // block's 16 batch rows

    if (tid == 0) {
        pdone[0] = pdone[1] = pdone[2] = pdone[3] = 0;
        hdone1 = 0; go = 0;
    }

    // one-time W staging into fragment order: idx = (kb*2+half)*64 + l
    for (int idx = tid; idx < 8192; idx += TPB) {
        int kb = idx >> 7, j = (idx >> 6) & 1, l = idx & 63;
        wfrag[idx] = *(const f16x8*)(WT + (size_t)(n0 + j * 16 + (l & 15)) * H_SZ
                                        + kb * 32 + (l >> 4) * 8);
    }
    __syncthreads();   // the ONLY block-wide barrier (covers flag init)

    int wave = tid >> 6, lane = tid & 63;

    if (wave == 4) {
        // dedicated clock keep-alive: 4 independent FMA chains, poll LDS exit flag
        float c0 = 1.0f + lane, c1 = 2.0f, c2 = 3.0f, c3 = 4.0f;
        const float k1 = 1.0000001f, k2 = 1.0e-30f;
        while (__hip_atomic_load(&go, __ATOMIC_RELAXED, __HIP_MEMORY_SCOPE_WORKGROUP) < T_STEPS) {
#pragma unroll
            for (int z = 0; z < 64; z++) {
                c0 = __builtin_fmaf(c0, k1, k2);
                c1 = __builtin_fmaf(c1, k1, k2);
                c2 = __builtin_fmaf(c2, k1, k2);
                c3 = __builtin_fmaf(c3, k1, k2);
            }
        }
        __asm__ volatile("" :: "v"(c0), "v"(c1), "v"(c2), "v"(c3));
        return;
    }

    int q = lane >> 4, r = lane & 15;
    unsigned int* aline = ctr + (g * 2 + (bid & 1)) * 32;   // group parity arrival line

    // reducer-layout x_proj prefetch for t=0 (waves 0,1 only):
    // elem s -> row = (lane>>4)+4s, col = lane&15, column half = wave
    float xp[4];
    if (wave < 2) {
#pragma unroll
        for (int s = 0; s < 4; s++)
            xp[s] = out[(size_t)(row0 + q + 4 * s) * H_SZ + n0 + wave * 16 + r];
    }

    for (int t = 0; t < T_STEPS; t++) {
        const _Float16* hp;
        _Float16*       hn;
        if constexpr (CHAIN) {
            hp = hbase + (size_t)t * HBUF;
            hn = hbase + (size_t)(t + 1) * HBUF;
        } else {
            hp = (t & 1) ? hb1 : hbase;
            hn = (t & 1) ? hbase : hb1;
        }
        float* out_t = out + (size_t)t * B_SZ * H_SZ;
        int tg = t + 1;

        // ---- A stream: this wave's K-slice, all 16 loads in flight ----
        const _Float16* arow = hp + (size_t)(row0 + r) * H_SZ + q * 8;
        f16x8 abuf[16];
#pragma unroll
        for (int p = 0; p < 16; p++) {
            if constexpr (CHAIN) {
                abuf[p] = *(const f16x8*)(arow + (wave * 16 + p) * 32);
            } else {
                union { unsigned long long u[2]; f16x8 v; } au;
                au.u[0] = __hip_atomic_load((unsigned long long*)(arow + (wave * 16 + p) * 32),
                                            __ATOMIC_RELAXED, __HIP_MEMORY_SCOPE_AGENT);
                au.u[1] = __hip_atomic_load((unsigned long long*)(arow + (wave * 16 + p) * 32) + 1,
                                            __ATOMIC_RELAXED, __HIP_MEMORY_SCOPE_AGENT);
                abuf[p] = au.v;
            }
        }
        f32x4 acc[2] = {};
#pragma unroll
        for (int p = 0; p < 16; p++) {
            int kb = wave * 16 + p;
            acc[0] = __builtin_amdgcn_mfma_f32_16x16x32_f16(abuf[p], wfrag[kb * 128 + lane],      acc[0], 0, 0, 0);
            acc[1] = __builtin_amdgcn_mfma_f32_16x16x32_f16(abuf[p], wfrag[kb * 128 + 64 + lane], acc[1], 0, 0, 0);
        }

        // partials to LDS (b128, conflict-free), then flag
#pragma unroll
        for (int h = 0; h < 2; h++)
            *(f32x4*)&part[wave][h][lane * 4] = acc[h];
        __asm__ volatile("s_waitcnt lgkmcnt(0)" ::: "memory");
        if (lane == 0)
            __hip_atomic_store(&pdone[wave], tg, __ATOMIC_RELAXED, __HIP_MEMORY_SCOPE_WORKGROUP);

        if (wave >= 2) {
            if (t == T_STEPS - 1) break;
            while (__hip_atomic_load(&go, __ATOMIC_RELAXED, __HIP_MEMORY_SCOPE_WORKGROUP) < tg) { }
            continue;
        }

        // ---- reducer path (wave 0 = col half 0, wave 1 = col half 1) ----
        for (int w = 0; w < 4; w++)
            if (w != wave)
                while (__hip_atomic_load(&pdone[w], __ATOMIC_RELAXED, __HIP_MEMORY_SCOPE_WORKGROUP) < tg) { }
        __asm__ volatile("" ::: "memory");

        bool last = (t == T_STEPS - 1);
#pragma unroll
        for (int s = 0; s < 4; s++) {
            int row = q + 4 * s;                  // local row 0..15
            int idx = (s * 16 + r) * 4 + q;       // producer layout: ((row>>2)*16+col)*4+(row&3)
            float sum = part[0][wave][idx] + part[1][wave][idx]
                      + part[2][wave][idx] + part[3][wave][idx];
            float v = tanhf(sum * W_INV_SCALE + xp[s]);
            size_t o = (size_t)(row0 + row) * H_SZ + n0 + wave * 16 + r;
            out_t[o] = v;
            if (last) final_out[o] = v;
            hsl[row * 32 + wave * 16 + r] = (_Float16)v;
        }
        if (last) {
            if (wave == 0 && lane == 0)
                __hip_atomic_store(&go, T_STEPS, __ATOMIC_RELAXED, __HIP_MEMORY_SCOPE_WORKGROUP);
            break;
        }

        // prefetch next step's x_proj (h-independent; overlaps h store)
        const float* out_t1 = out_t + B_SZ * H_SZ;
#pragma unroll
        for (int s = 0; s < 4; s++)
            xp[s] = out_t1[(size_t)(row0 + q + 4 * s) * H_SZ + n0 + wave * 16 + r];

        // h store: this wave's column half, 16 rows x 4 ull = 64 ull, 1/lane
        __asm__ volatile("s_waitcnt lgkmcnt(0)" ::: "memory");
        {
            int rl = lane >> 2, pi = wave * 4 + (lane & 3);
            unsigned long long vv = ((const unsigned long long*)hsl)[rl * 8 + pi];
            __hip_atomic_store((unsigned long long*)(hn + (size_t)(row0 + rl) * H_SZ + n0) + pi,
                               vv, __ATOMIC_RELAXED, __HIP_MEMORY_SCOPE_AGENT);
        }
        __builtin_amdgcn_s_waitcnt(0);   // h stores acked at coherence point

        if (wave == 1) {
            if (lane == 0)
                __hip_atomic_store(&hdone1, tg, __ATOMIC_RELAXED, __HIP_MEMORY_SCOPE_WORKGROUP);
            while (__hip_atomic_load(&go, __ATOMIC_RELAXED, __HIP_MEMORY_SCOPE_WORKGROUP) < tg) { }
            continue;
        }
        // wave 0: group barrier (flat: add + poll both parity lines)
        while (__hip_atomic_load(&hdone1, __ATOMIC_RELAXED, __HIP_MEMORY_SCOPE_WORKGROUP) < tg) { }
        if (lane == 0)
            __hip_atomic_fetch_add(aline, 1u, __ATOMIC_RELAXED, __HIP_MEMORY_SCOPE_AGENT);
        unsigned int line_tgt = (unsigned int)tg * 32u;
        for (;;) {
            unsigned int v = __hip_atomic_load(ctr + (g * 2 + (lane & 1)) * 32,
                                               __ATOMIC_RELAXED, __HIP_MEMORY_SCOPE_AGENT);
            if (__ballot(v < line_tgt) == 0ull) break;
        }
        if (lane == 0)
            __hip_atomic_store(&go, tg, __ATOMIC_RELAXED, __HIP_MEMORY_SCOPE_WORKGROUP);
    }
}

// ---------------- launcher ----------------

extern "C" void kernel_launch(void* const* d_in, const int* in_sizes, int n_in,
                              void* d_out, int out_size, void* d_ws, size_t ws_size,
                              hipStream_t stream) {
    const float* inputs = (const float*)d_in[0];   // [T,B,D]
    const float* state  = (const float*)d_in[1];   // [B,H]
    const float* W_xh   = (const float*)d_in[2];   // [D,H]
    const float* W_hh   = (const float*)d_in[3];   // [H,H]
    const float* b_h    = (const float*)d_in[4];   // [H]
    float* out = (float*)d_out;
    char* ws = (char*)d_ws;

    const size_t MB = 1ull << 20;
    // chain layout: [WxT 4MB][WhT 8MB][ctr 8KB][h chain: 257 x 256KB]
    // inputs_f16 (32 MB, dead after gemm) aliases chain slots h_1..h_128.
    const size_t OFF_WXT   = 0;
    const size_t OFF_WHT   = 4 * MB;
    const size_t OFF_CTR   = 12 * MB;
    const size_t OFF_CHAIN = 12 * MB + 8192;
    const size_t NEED_CHAIN = OFF_CHAIN + (size_t)(T_STEPS + 1) * HBUF * 2;

    // fallback (ping-pong) layout
    const size_t F_IN  = 0;
    const size_t F_WXT = F_IN  + (size_t)T_STEPS * B_SZ * D_SZ * 2;
    const size_t F_WHT = F_WXT + (size_t)H_SZ * D_SZ * 2;
    const size_t F_H0  = F_WHT + (size_t)H_SZ * H_SZ * 2;
    const size_t F_H1  = F_H0  + (size_t)HBUF * 2;
    const size_t F_CTR = F_H1  + (size_t)HBUF * 2;
    const size_t NEED_PP = F_CTR + 4096;

    const int n_in_el = T_STEPS * B_SZ * D_SZ;   // 16,777,216
    dim3 g1((T_STEPS * B_SZ) / 128, H_SZ / 128);
    float* final_out = out + (size_t)T_STEPS * B_SZ * H_SZ;

    if (ws_size >= NEED_CHAIN) {
        _Float16* WxT    = (_Float16*)(ws + OFF_WXT);
        _Float16* WhT    = (_Float16*)(ws + OFF_WHT);
        unsigned int* ctr = (unsigned int*)(ws + OFF_CTR);
        _Float16* hchain = (_Float16*)(ws + OFF_CHAIN);          // h_0
        _Float16* inputs_f16 = hchain + HBUF;                    // alias h_1..h_128
        _Float16* hb1 = nullptr;

        cvt_f32_f16<<<(n_in_el + 255) / 256, 256, 0, stream>>>(inputs, inputs_f16, n_in_el, 1.0f);
        transpose_to_f16<<<(D_SZ * H_SZ + 255) / 256, 256, 0, stream>>>(W_xh, WxT, D_SZ, 11, W_SCALE);
        transpose_to_f16<<<(H_SZ * H_SZ + 255) / 256, 256, 0, stream>>>(W_hh, WhT, H_SZ, 11, W_SCALE);
        cvt_f32_f16<<<(B_SZ * H_SZ + 255) / 256, 256, 0, stream>>>(state, hchain, B_SZ * H_SZ, 1.0f);
        init_ctrs<<<4, 256, 0, stream>>>(ctr);

        gemm_xproj<<<g1, 256, 0, stream>>>(inputs_f16, WxT, b_h, out,
                                           T_STEPS * B_SZ, H_SZ, D_SZ);

        void* args[] = { (void*)&hchain, (void*)&hb1, (void*)&WhT,
                         (void*)&out, (void*)&final_out, (void*)&ctr };
        hipLaunchCooperativeKernel((void*)rnn_persist<true>, dim3(NBLK), dim3(TPB),
                                   args, 0, stream);
    } else {
        if (ws_size < NEED_PP) return;
        _Float16* inputs_f16 = (_Float16*)(ws + F_IN);
        _Float16* WxT    = (_Float16*)(ws + F_WXT);
        _Float16* WhT    = (_Float16*)(ws + F_WHT);
        _Float16* hbuf0  = (_Float16*)(ws + F_H0);
        _Float16* hbuf1  = (_Float16*)(ws + F_H1);
        unsigned int* ctr = (unsigned int*)(ws + F_CTR);

        cvt_f32_f16<<<(n_in_el + 255) / 256, 256, 0, stream>>>(inputs, inputs_f16, n_in_el, 1.0f);
        transpose_to_f16<<<(D_SZ * H_SZ + 255) / 256, 256, 0, stream>>>(W_xh, WxT, D_SZ, 11, W_SCALE);
        transpose_to_f16<<<(H_SZ * H_SZ + 255) / 256, 256, 0, stream>>>(W_hh, WhT, H_SZ, 11, W_SCALE);
        cvt_f32_f16<<<(B_SZ * H_SZ + 255) / 256, 256, 0, stream>>>(state, hbuf0, B_SZ * H_SZ, 1.0f);
        init_ctrs<<<4, 256, 0, stream>>>(ctr);

        gemm_xproj<<<g1, 256, 0, stream>>>(inputs_f16, WxT, b_h, out,
                                           T_STEPS * B_SZ, H_SZ, D_SZ);

        void* args[] = { (void*)&hbuf0, (void*)&hbuf1, (void*)&WhT,
                         (void*)&out, (void*)&final_out, (void*)&ctr };
        hipLaunchCooperativeKernel((void*)rnn_persist<false>, dim3(NBLK), dim3(TPB),
                                   args, 0, stream);
    }
}